// Round 4
// baseline (527.696 us; speedup 1.0000x reference)
//
#include <hip/hip_runtime.h>

#define L 4096
#define HH 64
#define CC 128
#define BB 2
#define KD 1152   // C*9

typedef _Float16 f16;
typedef _Float16 f16x8 __attribute__((ext_vector_type(8)));
typedef float f32x4 __attribute__((ext_vector_type(4)));

__device__ __forceinline__ void gl_lds16(const f16* g, f16* l) {
  __builtin_amdgcn_global_load_lds(
      (const __attribute__((address_space(1))) void*)g,
      (__attribute__((address_space(3))) void*)l, 16, 0, 0);
}

// sigma: involution converting row-major flat <-> col-major flat (64x64)
__device__ __forceinline__ int sigma_(int j) { return ((j & 63) << 6) | (j >> 6); }

// full 9-tap fused score from S (reference wrap semantics), scalar fallback for edges
__device__ float fuse9(const f16* __restrict__ Sb, int k, int j) {
  float acc = 0.f;
  int cK = sigma_(k), cQ = sigma_(j);
#pragma unroll
  for (int u = -1; u <= 1; ++u) {
    int a = cK + u, bq = cQ + u;
    if ((unsigned)a < L && (unsigned)bq < L) {
      int r = sigma_(a), c = sigma_(bq);
#pragma unroll
      for (int t = -1; t <= 1; ++t) {
        int rr = r + t, cc = c + t;
        if ((unsigned)rr < L && (unsigned)cc < L) acc += (float)Sb[(size_t)rr * L + cc];
      }
    }
  }
  return acc;
}

// interior 9-tap: T3[k][q] = Sb[k*L+q + delta*(L+1)], delta in {-65..65 pattern}
__device__ __forceinline__ float fuse9_int(const f16* __restrict__ base) {
  const int D = L + 1;  // 4097
  float acc = 0.f;
  acc += (float)base[-65 * D]; acc += (float)base[-64 * D]; acc += (float)base[-63 * D];
  acc += (float)base[-D];      acc += (float)base[0];       acc += (float)base[D];
  acc += (float)base[63 * D];  acc += (float)base[64 * D];  acc += (float)base[65 * D];
  return acc;
}

// ---------------- kernel 1a: im2col of f (FP) and normalized b (WN), f16 ----------------
__global__ __launch_bounds__(256) void k_prep_patches(
    const float* __restrict__ f, const float* __restrict__ b,
    f16* __restrict__ WN, f16* __restrict__ FP) {
  int wid = threadIdx.x >> 6;
  int lane = threadIdx.x & 63;
  int loc = blockIdx.x * 4 + wid;          // 0..8191 = batch*L + k
  int batch = loc >> 12;
  int k = loc & (L - 1);
  int ky = k >> 6, kx = k & 63;
  const float* bp = b + (size_t)batch * CC * L;
  const float* fp_ = f + (size_t)batch * CC * L;
  float bv[18], fv[18];
  float ss = 0.f;
#pragma unroll
  for (int it = 0; it < 18; ++it) {
    int d = it * 64 + lane;
    int c = d / 9;
    int r = d - c * 9;
    int yy = ky + (r / 3) - 1, xx = kx + (r % 3) - 1;
    bool ok = (yy >= 0 && yy < 64 && xx >= 0 && xx < 64);
    float vb = ok ? bp[(size_t)c * L + yy * 64 + xx] : 0.f;
    float vf = ok ? fp_[(size_t)c * L + yy * 64 + xx] : 0.f;
    bv[it] = vb; fv[it] = vf;
    ss += vb * vb;
  }
#pragma unroll
  for (int m = 32; m >= 1; m >>= 1) ss += __shfl_xor(ss, m, 64);
  float scale = 1.f / fmaxf(sqrtf(ss), 1e-4f);
  f16* wn = WN + (size_t)loc * KD;
  f16* fpo = FP + (size_t)loc * KD;
#pragma unroll
  for (int it = 0; it < 18; ++it) {
    int d = it * 64 + lane;
    wn[d] = (f16)(bv[it] * scale);
    fpo[d] = (f16)(fv[it]);
  }
}

// ---------------- kernel 1b: shifted+masked f16 copies of b for the 4 taps ---------------
__global__ void k_prep_bm(const float* __restrict__ b, f16* __restrict__ bm) {
  int idx = blockIdx.x * 256 + threadIdx.x;  // total 4*2*128*4096
  int k = idx & (L - 1);
  int c = (idx >> 12) & (CC - 1);
  int bt = idx >> 19;           // tap*2 + batch
  int batch = bt & 1;
  int tap = bt >> 1;
  int di = 1 - (tap >> 1), dj = 1 - (tap & 1);
  int ky = k >> 6, kx = k & 63;
  float v = 0.f;
  if (ky + di < 64 && kx + dj < 64)
    v = b[((size_t)batch * CC + c) * L + k + di * 64 + dj];
  bm[idx] = (f16)v;
}

// ---------------- kernel 1c: mask validity mm[k] -----------------------------------------
__global__ void k_prep_mm(const float* __restrict__ mask, float* __restrict__ mmv) {
  int k = blockIdx.x * 256 + threadIdx.x;
  if (k >= L) return;
  int ky = k >> 6, kx = k & 63;
  float s = 0.f;
  for (int i = 0; i < 3; ++i)
    for (int j = 0; j < 3; ++j) {
      int yy = ky + i - 1, xx = kx + j - 1;
      if (yy >= 0 && yy < 64 && xx >= 0 && xx < 64) s += mask[yy * 64 + xx];
    }
  mmv[k] = (s == 0.f) ? 1.f : 0.f;
}

// ---------------- kernel 2: scores GEMM  S[k,q] = sum_d WN[k,d]*FP[q,d], f16 out ---------
__global__ __launch_bounds__(256) void k_gemm_scores(
    const f16* __restrict__ WN, const f16* __restrict__ FP, f16* __restrict__ S) {
  __shared__ f16 As[128 * 32];
  __shared__ f16 Bs[128 * 32];
  int qt = blockIdx.x, kt = blockIdx.y, batch = blockIdx.z;
  int tid = threadIdx.x, wid = tid >> 6, lane = tid & 63;
  int wr = wid >> 1, wc = wid & 1;
  const f16* Abase = WN + ((size_t)batch * L + kt * 128) * KD;
  const f16* Bbase = FP + ((size_t)batch * L + qt * 128) * KD;
  f32x4 acc[4][4] = {};
  int srow = lane >> 2;          // 0..15
  int scol = (lane & 3) * 8;     // f16 offset within 32
  for (int kk = 0; kk < KD; kk += 32) {
    __syncthreads();
    {
      int r0 = wid * 32 + srow;
      gl_lds16(Abase + (size_t)r0 * KD + kk + scol, As + r0 * 32 + scol);
      gl_lds16(Abase + (size_t)(r0 + 16) * KD + kk + scol, As + (r0 + 16) * 32 + scol);
      gl_lds16(Bbase + (size_t)r0 * KD + kk + scol, Bs + r0 * 32 + scol);
      gl_lds16(Bbase + (size_t)(r0 + 16) * KD + kk + scol, Bs + (r0 + 16) * 32 + scol);
    }
    __syncthreads();
    f16x8 af[4], bf[4];
    int kb = (lane >> 4) * 8;
    int rA = wr * 64 + (lane & 15);
    int rB = wc * 64 + (lane & 15);
#pragma unroll
    for (int m = 0; m < 4; ++m) af[m] = *(const f16x8*)(As + (rA + m * 16) * 32 + kb);
#pragma unroll
    for (int n = 0; n < 4; ++n) bf[n] = *(const f16x8*)(Bs + (rB + n * 16) * 32 + kb);
#pragma unroll
    for (int m = 0; m < 4; ++m)
#pragma unroll
      for (int n = 0; n < 4; ++n)
        acc[m][n] = __builtin_amdgcn_mfma_f32_16x16x32_f16(af[m], bf[n], acc[m][n], 0, 0, 0);
  }
  f16* Srow = S + (size_t)batch * L * L;
  int kbase = kt * 128 + wr * 64 + (lane >> 4) * 4;
  int qbase = qt * 128 + wc * 64 + (lane & 15);
#pragma unroll
  for (int m = 0; m < 4; ++m)
#pragma unroll
    for (int r = 0; r < 4; ++r) {
      f16* dst = Srow + (size_t)(kbase + m * 16 + r) * L + qbase;
#pragma unroll
      for (int n = 0; n < 4; ++n) dst[n * 16] = (f16)acc[m][n][r];
    }
}

// ---------------- kernel 3: fused stencil + online softmax partial stats -----------------
__global__ __launch_bounds__(256) void k_softmax_stats(
    const f16* __restrict__ S, const float* __restrict__ mmv,
    float* __restrict__ pm, float* __restrict__ pl) {
  int q = blockIdx.x * 256 + threadIdx.x;
  int kc = blockIdx.y, batch = blockIdx.z;
  const f16* Sb = S + (size_t)batch * L * L;
  bool qint = (q >= 66 && q <= 4030);
  float m = -3.0e38f, l = 0.f;
  int k0 = kc * 64;
#pragma unroll 2
  for (int kk = 0; kk < 64; ++kk) {
    int k = k0 + kk;
    float logit = 0.f;
    if (mmv[k] != 0.f) {
      float acc;
      if (qint && k >= 66 && k <= 4030)
        acc = fuse9_int(Sb + (size_t)k * L + q);
      else
        acc = fuse9(Sb, k, q);
      logit = 10.f * acc;
    }
    float nm = fmaxf(m, logit);
    l = l * __expf(m - nm) + __expf(logit - nm);
    m = nm;
  }
  int qi = batch * L + q;
  pm[kc * (BB * L) + qi] = m;
  pl[kc * (BB * L) + qi] = l;
}

// ---------------- kernel 3b: combine partials -------------------------------------------
__global__ void k_softmax_reduce(const float* __restrict__ pm, const float* __restrict__ pl,
                                 float* __restrict__ Mq, float* __restrict__ Lq) {
  int qi = blockIdx.x * 256 + threadIdx.x;
  if (qi >= BB * L) return;
  float M = -3.0e38f;
#pragma unroll 8
  for (int i = 0; i < 64; ++i) M = fmaxf(M, pm[i * (BB * L) + qi]);
  float Ls = 0.f;
#pragma unroll 8
  for (int i = 0; i < 64; ++i) Ls += pl[i * (BB * L) + qi] * __expf(pm[i * (BB * L) + qi] - M);
  Mq[qi] = M;
  Lq[qi] = Ls;
}

// ---------------- kernel 4: fused stencil + exp -> attn (f16, [b][k][q]) -----------------
__global__ __launch_bounds__(256) void k_attn(
    const f16* __restrict__ S, const float* __restrict__ mmv,
    const float* __restrict__ Mq, const float* __restrict__ Lq,
    f16* __restrict__ attn) {
  int q = blockIdx.x * 256 + threadIdx.x;
  int kc = blockIdx.y, batch = blockIdx.z;
  const f16* Sb = S + (size_t)batch * L * L;
  f16* An = attn + (size_t)batch * L * L;
  int qi = batch * L + q;
  float M = Mq[qi];
  float inv = 1.f / Lq[qi];
  bool qint = (q >= 66 && q <= 4030);
  int k0 = kc * 64;
#pragma unroll 2
  for (int kk = 0; kk < 64; ++kk) {
    int k = k0 + kk;
    float v = 0.f;
    if (mmv[k] != 0.f) {
      float acc;
      if (qint && k >= 66 && k <= 4030)
        acc = fuse9_int(Sb + (size_t)k * L + q);
      else
        acc = fuse9(Sb, k, q);
      v = __expf(10.f * acc - M) * inv;
    }
    An[(size_t)k * L + q] = (f16)v;
  }
}

// ---------------- kernel 5: aggregation, K-split partials --------------------------------
__global__ __launch_bounds__(512) void k_agg(
    const f16* __restrict__ attn, const f16* __restrict__ bm, float* __restrict__ part) {
  __shared__ f16 Asm[512 * 32];   // [R=tap*128+c][32kk], chunk-swizzled: phys = log ^ ((R>>1)&3)
  __shared__ f16 Bt[136 * 40];    // [pp][kk], kk-chunk swizzled: phys = log ^ ((pp>>3)&3)
  int pt = blockIdx.x, ks = blockIdx.y, batch = blockIdx.z;
  int p0 = pt * 64;
  int tid = threadIdx.x, wid = tid >> 6, lane = tid & 63;
  int wr = wid >> 1, wc = wid & 1;
  const f16* attnB = attn + (size_t)batch * L * L;
  f32x4 acc[2][2] = {};
  int kend = ks * 1024 + 1024;
  for (int k0 = ks * 1024; k0 < kend; k0 += 32) {
    __syncthreads();
#pragma unroll
    for (int i = 0; i < 4; ++i) {
      int R = wid * 64 + i * 16 + (lane >> 2);
      int tap = R >> 7, c = R & 127;
      int chl = (lane & 3) ^ ((R >> 1) & 3);
      const f16* g = bm + (((size_t)(tap * 2 + batch) * CC + c) * L) + k0 + chl * 8;
      gl_lds16(g, Asm + R * 32 + (lane & 3) * 8);
    }
    for (int tau = tid; tau < 544; tau += 512) {
      int kk = tau / 17, ch = tau - kk * 17;
      int pbase = p0 + ch * 8;
      const f16* src = attnB + (size_t)(k0 + kk) * L + pbase;
      f16 v[8];
      if (pbase + 7 < L) {
        f16x8 vv = *(const f16x8*)src;
#pragma unroll
        for (int e = 0; e < 8; ++e) v[e] = vv[e];
      } else {
#pragma unroll
        for (int e = 0; e < 8; ++e) v[e] = (pbase + e < L) ? src[e] : (f16)0.f;
      }
#pragma unroll
      for (int e = 0; e < 8; ++e) {
        int pp = ch * 8 + e;
        Bt[pp * 40 + (((kk >> 3) ^ ((pp >> 3) & 3)) * 8) + (kk & 7)] = v[e];
      }
    }
    __syncthreads();
#pragma unroll
    for (int tap = 0; tap < 4; ++tap) {
      int dlt = (tap >> 1) * 64 + (tap & 1);
      f16x8 af[2], bf[2];
#pragma unroll
      for (int m = 0; m < 2; ++m) {
        int R = tap * 128 + wr * 32 + m * 16 + (lane & 15);
        int ph = (lane >> 4) ^ ((R >> 1) & 3);
        af[m] = *(const f16x8*)(Asm + R * 32 + ph * 8);
      }
#pragma unroll
      for (int n = 0; n < 2; ++n) {
        int pp = wc * 32 + n * 16 + (lane & 15) + dlt;
        int ph = (lane >> 4) ^ ((pp >> 3) & 3);
        bf[n] = *(const f16x8*)(Bt + pp * 40 + ph * 8);
      }
#pragma unroll
      for (int m = 0; m < 2; ++m)
#pragma unroll
        for (int n = 0; n < 2; ++n)
          acc[m][n] = __builtin_amdgcn_mfma_f32_16x16x32_f16(af[m], bf[n], acc[m][n], 0, 0, 0);
    }
  }
  int cb = wr * 32 + (lane >> 4) * 4;
  int pb = p0 + wc * 32 + (lane & 15);
#pragma unroll
  for (int m = 0; m < 2; ++m)
#pragma unroll
    for (int n = 0; n < 2; ++n)
#pragma unroll
      for (int r = 0; r < 4; ++r) {
        int c = cb + m * 16 + r;
        int p = pb + n * 16;
        part[(((size_t)ks * 2 + batch) * CC + c) * L + p] = acc[m][n][r];
      }
}

// ---------------- kernel 5b: sum K-split partials, scale, border mask --------------------
__global__ void k_agg_reduce(const float* __restrict__ part, float* __restrict__ out) {
  int idx = blockIdx.x * 256 + threadIdx.x;   // 2*128*4096
  int p = idx & (L - 1);
  float s = 0.f;
#pragma unroll
  for (int ks = 0; ks < 4; ++ks) s += part[(size_t)ks * (2 * CC * L) + idx];
  int u = p >> 6, v = p & 63;
  out[idx] = (u < 63 && v < 63) ? s * 0.25f : 0.f;
}

extern "C" void kernel_launch(void* const* d_in, const int* in_sizes, int n_in,
                              void* d_out, int out_size, void* d_ws, size_t ws_size,
                              hipStream_t stream) {
  const float* f = (const float*)d_in[0];
  const float* b = (const float*)d_in[1];
  const float* mask = (const float*)d_in[2];
  float* out = (float*)d_out;
  char* ws = (char*)d_ws;

  // Lifetimes: WN/FP(prep->gemm); S(gemm->attn); attn(attn->agg) in its own region.
  f16* WN    = (f16*)(ws + 0);             // 18,874,368
  f16* FP    = (f16*)(ws + 18874368);      // 18,874,368
  f16* attn  = (f16*)(ws + 37748736);      // 67,108,864 (over dead WN/FP + slack)
  f16* S     = (f16*)(ws + 134217728);     // 67,108,864
  f16* bm    = (f16*)(ws + 201326592);     // 8,388,608
  float* part= (float*)(ws + 209715200);   // 16,777,216
  float* pm  = (float*)(ws + 226492416);   // 2,097,152
  float* pl  = (float*)(ws + 228589568);   // 2,097,152
  float* mmv = (float*)(ws + 230686720);   // 16,384
  float* Mq  = (float*)(ws + 230703104);   // 32,768
  float* Lq  = (float*)(ws + 230735872);   // 32,768

  k_prep_patches<<<dim3(2048), dim3(256), 0, stream>>>(f, b, WN, FP);
  k_prep_bm<<<dim3(16384), dim3(256), 0, stream>>>(b, bm);
  k_prep_mm<<<dim3(16), dim3(256), 0, stream>>>(mask, mmv);
  k_gemm_scores<<<dim3(32, 32, 2), dim3(256), 0, stream>>>(WN, FP, S);
  k_softmax_stats<<<dim3(16, 64, 2), dim3(256), 0, stream>>>(S, mmv, pm, pl);
  k_softmax_reduce<<<dim3(32), dim3(256), 0, stream>>>(pm, pl, Mq, Lq);
  k_attn<<<dim3(16, 64, 2), dim3(256), 0, stream>>>(S, mmv, Mq, Lq, attn);
  k_agg<<<dim3(64, 4, 2), dim3(512), 0, stream>>>(attn, bm, part);
  k_agg_reduce<<<dim3(4096), dim3(256), 0, stream>>>(part, out);
}

// Round 5
// 393.763 us; speedup vs baseline: 1.3401x; 1.3401x over previous
//
#include <hip/hip_runtime.h>

#define L 4096
#define HH 64
#define CC 128
#define BB 2
#define KD 1152   // C*9

typedef _Float16 f16;
typedef _Float16 f16x8 __attribute__((ext_vector_type(8)));
typedef float f32x4 __attribute__((ext_vector_type(4)));

__device__ __forceinline__ void gl_lds16(const f16* g, f16* l) {
  __builtin_amdgcn_global_load_lds(
      (const __attribute__((address_space(1))) void*)g,
      (__attribute__((address_space(3))) void*)l, 16, 0, 0);
}

// sigma: involution converting row-major flat <-> col-major flat (64x64)
__device__ __forceinline__ int sigma_(int j) { return ((j & 63) << 6) | (j >> 6); }

// full 9-tap fused score from S (reference wrap semantics), scalar (edge columns)
__device__ float fuse9(const f16* __restrict__ Sb, int k, int j) {
  float acc = 0.f;
  int cK = sigma_(k), cQ = sigma_(j);
#pragma unroll
  for (int u = -1; u <= 1; ++u) {
    int a = cK + u, bq = cQ + u;
    if ((unsigned)a < L && (unsigned)bq < L) {
      int r = sigma_(a), c = sigma_(bq);
#pragma unroll
      for (int t = -1; t <= 1; ++t) {
        int rr = r + t, cc = c + t;
        if ((unsigned)rr < L && (unsigned)cc < L) acc += (float)Sb[(size_t)rr * L + cc];
      }
    }
  }
  return acc;
}

// ---------------- kernel 1a: im2col of f (FP) and normalized b (WN), f16 ----------------
__global__ __launch_bounds__(256) void k_prep_patches(
    const float* __restrict__ f, const float* __restrict__ b,
    f16* __restrict__ WN, f16* __restrict__ FP) {
  int wid = threadIdx.x >> 6;
  int lane = threadIdx.x & 63;
  int loc = blockIdx.x * 4 + wid;          // 0..8191 = batch*L + k
  int batch = loc >> 12;
  int k = loc & (L - 1);
  int ky = k >> 6, kx = k & 63;
  const float* bp = b + (size_t)batch * CC * L;
  const float* fp_ = f + (size_t)batch * CC * L;
  float bv[18], fv[18];
  float ss = 0.f;
#pragma unroll
  for (int it = 0; it < 18; ++it) {
    int d = it * 64 + lane;
    int c = d / 9;
    int r = d - c * 9;
    int yy = ky + (r / 3) - 1, xx = kx + (r % 3) - 1;
    bool ok = (yy >= 0 && yy < 64 && xx >= 0 && xx < 64);
    float vb = ok ? bp[(size_t)c * L + yy * 64 + xx] : 0.f;
    float vf = ok ? fp_[(size_t)c * L + yy * 64 + xx] : 0.f;
    bv[it] = vb; fv[it] = vf;
    ss += vb * vb;
  }
#pragma unroll
  for (int m = 32; m >= 1; m >>= 1) ss += __shfl_xor(ss, m, 64);
  float scale = 1.f / fmaxf(sqrtf(ss), 1e-4f);
  f16* wn = WN + (size_t)loc * KD;
  f16* fpo = FP + (size_t)loc * KD;
#pragma unroll
  for (int it = 0; it < 18; ++it) {
    int d = it * 64 + lane;
    wn[d] = (f16)(bv[it] * scale);
    fpo[d] = (f16)(fv[it]);
  }
}

// ---------------- kernel 1b: shifted+masked f16 copies of b for the 4 taps ---------------
__global__ void k_prep_bm(const float* __restrict__ b, f16* __restrict__ bm) {
  int idx = blockIdx.x * 256 + threadIdx.x;  // total 4*2*128*4096
  int k = idx & (L - 1);
  int c = (idx >> 12) & (CC - 1);
  int bt = idx >> 19;           // tap*2 + batch
  int batch = bt & 1;
  int tap = bt >> 1;
  int di = 1 - (tap >> 1), dj = 1 - (tap & 1);
  int ky = k >> 6, kx = k & 63;
  float v = 0.f;
  if (ky + di < 64 && kx + dj < 64)
    v = b[((size_t)batch * CC + c) * L + k + di * 64 + dj];
  bm[idx] = (f16)v;
}

// ---------------- kernel 1c: mask validity mm[k] -----------------------------------------
__global__ void k_prep_mm(const float* __restrict__ mask, float* __restrict__ mmv) {
  int k = blockIdx.x * 256 + threadIdx.x;
  if (k >= L) return;
  int ky = k >> 6, kx = k & 63;
  float s = 0.f;
  for (int i = 0; i < 3; ++i)
    for (int j = 0; j < 3; ++j) {
      int yy = ky + i - 1, xx = kx + j - 1;
      if (yy >= 0 && yy < 64 && xx >= 0 && xx < 64) s += mask[yy * 64 + xx];
    }
  mmv[k] = (s == 0.f) ? 1.f : 0.f;
}

// ---------------- kernel 2: scores GEMM  S[k,q] = sum_d WN[k,d]*FP[q,d], f16 out ---------
__global__ __launch_bounds__(256) void k_gemm_scores(
    const f16* __restrict__ WN, const f16* __restrict__ FP, f16* __restrict__ S) {
  __shared__ f16 As[128 * 32];
  __shared__ f16 Bs[128 * 32];
  int qt = blockIdx.x, kt = blockIdx.y, batch = blockIdx.z;
  int tid = threadIdx.x, wid = tid >> 6, lane = tid & 63;
  int wr = wid >> 1, wc = wid & 1;
  const f16* Abase = WN + ((size_t)batch * L + kt * 128) * KD;
  const f16* Bbase = FP + ((size_t)batch * L + qt * 128) * KD;
  f32x4 acc[4][4] = {};
  int srow = lane >> 2;          // 0..15
  int scol = (lane & 3) * 8;     // f16 offset within 32
  for (int kk = 0; kk < KD; kk += 32) {
    __syncthreads();
    {
      int r0 = wid * 32 + srow;
      gl_lds16(Abase + (size_t)r0 * KD + kk + scol, As + r0 * 32 + scol);
      gl_lds16(Abase + (size_t)(r0 + 16) * KD + kk + scol, As + (r0 + 16) * 32 + scol);
      gl_lds16(Bbase + (size_t)r0 * KD + kk + scol, Bs + r0 * 32 + scol);
      gl_lds16(Bbase + (size_t)(r0 + 16) * KD + kk + scol, Bs + (r0 + 16) * 32 + scol);
    }
    __syncthreads();
    f16x8 af[4], bf[4];
    int kb = (lane >> 4) * 8;
    int rA = wr * 64 + (lane & 15);
    int rB = wc * 64 + (lane & 15);
#pragma unroll
    for (int m = 0; m < 4; ++m) af[m] = *(const f16x8*)(As + (rA + m * 16) * 32 + kb);
#pragma unroll
    for (int n = 0; n < 4; ++n) bf[n] = *(const f16x8*)(Bs + (rB + n * 16) * 32 + kb);
#pragma unroll
    for (int m = 0; m < 4; ++m)
#pragma unroll
      for (int n = 0; n < 4; ++n)
        acc[m][n] = __builtin_amdgcn_mfma_f32_16x16x32_f16(af[m], bf[n], acc[m][n], 0, 0, 0);
  }
  f16* Srow = S + (size_t)batch * L * L;
  int kbase = kt * 128 + wr * 64 + (lane >> 4) * 4;
  int qbase = qt * 128 + wc * 64 + (lane & 15);
#pragma unroll
  for (int m = 0; m < 4; ++m)
#pragma unroll
    for (int r = 0; r < 4; ++r) {
      f16* dst = Srow + (size_t)(kbase + m * 16 + r) * L + qbase;
#pragma unroll
      for (int n = 0; n < 4; ++n) dst[n * 16] = (f16)acc[m][n][r];
    }
}

// ---------------- kernel 3: fused stencil -> T3 + online softmax partials ----------------
// Interior q columns (q in [72, 4024)), vectorized 8-wide; all k (u-validity via sigma).
__global__ __launch_bounds__(256) void k_fuse_stats(
    const f16* __restrict__ S, const float* __restrict__ mmv,
    float* __restrict__ T3, float* __restrict__ pm, float* __restrict__ pl) {
  int tid = threadIdx.x;
  if (tid >= 247) return;
  int jc = blockIdx.x, kc = blockIdx.y, batch = blockIdx.z;
  int g = jc * 247 + tid;                  // 0..493
  int q0 = 72 + g * 8;                     // aligned, fully interior group
  const f16* Sb = S + (size_t)batch * L * L;
  float* Tb = T3 + (size_t)batch * L * L;
  float m8[8], l8[8];
#pragma unroll
  for (int e = 0; e < 8; ++e) { m8[e] = -3.0e38f; l8[e] = 0.f; }
  int cnt = 0;
  int k0 = kc * 16;
  for (int kk = 0; kk < 16; ++kk) {
    int k = k0 + kk;
    if (mmv[k] == 0.f) { ++cnt; continue; }
    float acc[8] = {0.f, 0.f, 0.f, 0.f, 0.f, 0.f, 0.f, 0.f};
    int cK = sigma_(k);
#pragma unroll
    for (int u = -1; u <= 1; ++u) {
      int a = cK + u;
      if ((unsigned)a >= L) continue;
      int r = sigma_(a);                   // = k + 64u for interior k
      const f16* cb = Sb + (size_t)r * L + (q0 + 64 * u);
      {
        f16x8 v = *(const f16x8*)cb;
#pragma unroll
        for (int e = 0; e < 8; ++e) acc[e] += (float)v[e];
      }
      if (r >= 1) {
        const f16* rm = cb - L;
        f16x8 v = *(const f16x8*)rm;
        acc[0] += (float)rm[-1];
#pragma unroll
        for (int e = 1; e < 8; ++e) acc[e] += (float)v[e - 1];
      }
      if (r <= L - 2) {
        const f16* rp = cb + L;
        f16x8 v = *(const f16x8*)rp;
#pragma unroll
        for (int e = 0; e < 7; ++e) acc[e] += (float)v[e + 1];
        acc[7] += (float)rp[8];
      }
    }
#pragma unroll
    for (int e = 0; e < 8; ++e) acc[e] *= 10.f;
    float* trow = Tb + (size_t)k * L + q0;
    *(f32x4*)trow = *(f32x4*)&acc[0];
    *(f32x4*)(trow + 4) = *(f32x4*)&acc[4];
#pragma unroll
    for (int e = 0; e < 8; ++e) {
      float nm = fmaxf(m8[e], acc[e]);
      l8[e] = l8[e] * __expf(m8[e] - nm) + __expf(acc[e] - nm);
      m8[e] = nm;
    }
  }
  float fc = (float)cnt;
  float om[8], ol[8];
#pragma unroll
  for (int e = 0; e < 8; ++e) {
    float nm = fmaxf(m8[e], 0.f);
    ol[e] = l8[e] * __expf(m8[e] - nm) + fc * __expf(-nm);
    om[e] = nm;
  }
  float* pmp = pm + (size_t)kc * (BB * L) + (size_t)batch * L + q0;
  float* plp = pl + (size_t)kc * (BB * L) + (size_t)batch * L + q0;
  *(f32x4*)pmp = *(f32x4*)&om[0]; *(f32x4*)(pmp + 4) = *(f32x4*)&om[4];
  *(f32x4*)plp = *(f32x4*)&ol[0]; *(f32x4*)(plp + 4) = *(f32x4*)&ol[4];
}

// ---------------- kernel 3e: edge q columns (144 cols), scalar fuse9 ---------------------
__global__ __launch_bounds__(256) void k_fuse_stats_edge(
    const f16* __restrict__ S, const float* __restrict__ mmv,
    float* __restrict__ T3, float* __restrict__ pm, float* __restrict__ pl) {
  int tid = threadIdx.x;
  if (tid >= 144) return;
  int q = (tid < 72) ? tid : (4024 + tid - 72);
  int kc = blockIdx.x, batch = blockIdx.y;
  const f16* Sb = S + (size_t)batch * L * L;
  float* Tb = T3 + (size_t)batch * L * L;
  float m = -3.0e38f, l = 0.f;
  int cnt = 0;
  int k0 = kc * 16;
  for (int kk = 0; kk < 16; ++kk) {
    int k = k0 + kk;
    if (mmv[k] == 0.f) { ++cnt; continue; }
    float logit = 10.f * fuse9(Sb, k, q);
    Tb[(size_t)k * L + q] = logit;
    float nm = fmaxf(m, logit);
    l = l * __expf(m - nm) + __expf(logit - nm);
    m = nm;
  }
  float nm = fmaxf(m, 0.f);
  l = l * __expf(m - nm) + (float)cnt * __expf(-nm);
  pm[(size_t)kc * (BB * L) + (size_t)batch * L + q] = nm;
  pl[(size_t)kc * (BB * L) + (size_t)batch * L + q] = l;
}

// ---------------- kernel 3b: combine partials (256 chunks) -------------------------------
__global__ void k_softmax_reduce(const float* __restrict__ pm, const float* __restrict__ pl,
                                 float* __restrict__ Mq, float* __restrict__ Lq) {
  int qi = blockIdx.x * 256 + threadIdx.x;
  if (qi >= BB * L) return;
  float M = -3.0e38f;
  for (int i = 0; i < 256; ++i) M = fmaxf(M, pm[(size_t)i * (BB * L) + qi]);
  float Ls = 0.f;
  for (int i = 0; i < 256; ++i) Ls += pl[(size_t)i * (BB * L) + qi] * __expf(pm[(size_t)i * (BB * L) + qi] - M);
  Mq[qi] = M;
  Lq[qi] = Ls;
}

// ---------------- kernel 4: attn = exp(T3 - M)/L (f16, [b][k][q]), vectorized ------------
__global__ __launch_bounds__(256) void k_attn(
    const float* __restrict__ T3, const float* __restrict__ mmv,
    const float* __restrict__ Mq, const float* __restrict__ Lq,
    f16* __restrict__ attn) {
  int tid = threadIdx.x;
  int jc = blockIdx.x, kc = blockIdx.y, batch = blockIdx.z;
  int q0 = (jc * 256 + tid) * 8;
  const float* Tb = T3 + (size_t)batch * L * L;
  f16* An = attn + (size_t)batch * L * L;
  float M[8], inv[8];
  const float* mq = Mq + (size_t)batch * L + q0;
  const float* lq = Lq + (size_t)batch * L + q0;
#pragma unroll
  for (int e = 0; e < 8; ++e) { M[e] = mq[e]; inv[e] = 1.f / lq[e]; }
  int k0 = kc * 32;
  for (int kk = 0; kk < 32; ++kk) {
    int k = k0 + kk;
    f16x8 w;
    if (mmv[k] != 0.f) {
      const float* trow = Tb + (size_t)k * L + q0;
      f32x4 a = *(const f32x4*)trow;
      f32x4 b2 = *(const f32x4*)(trow + 4);
#pragma unroll
      for (int e = 0; e < 4; ++e) w[e] = (f16)(__expf(a[e] - M[e]) * inv[e]);
#pragma unroll
      for (int e = 0; e < 4; ++e) w[4 + e] = (f16)(__expf(b2[e] - M[4 + e]) * inv[4 + e]);
    } else {
#pragma unroll
      for (int e = 0; e < 8; ++e) w[e] = (f16)0.f;
    }
    *(f16x8*)(An + (size_t)k * L + q0) = w;
  }
}

// ---------------- kernel 5: aggregation, K-split partials --------------------------------
__global__ __launch_bounds__(512) void k_agg(
    const f16* __restrict__ attn, const f16* __restrict__ bm, float* __restrict__ part) {
  __shared__ f16 Asm[512 * 32];   // [R=tap*128+c][32kk], chunk-swizzled: phys = log ^ ((R>>1)&3)
  __shared__ f16 Bt[136 * 40];    // [pp][kk], kk-chunk swizzled: phys = log ^ ((pp>>3)&3)
  int pt = blockIdx.x, ks = blockIdx.y, batch = blockIdx.z;
  int p0 = pt * 64;
  int tid = threadIdx.x, wid = tid >> 6, lane = tid & 63;
  int wr = wid >> 1, wc = wid & 1;
  const f16* attnB = attn + (size_t)batch * L * L;
  f32x4 acc[2][2] = {};
  int kend = ks * 1024 + 1024;
  for (int k0 = ks * 1024; k0 < kend; k0 += 32) {
    __syncthreads();
#pragma unroll
    for (int i = 0; i < 4; ++i) {
      int R = wid * 64 + i * 16 + (lane >> 2);
      int tap = R >> 7, c = R & 127;
      int chl = (lane & 3) ^ ((R >> 1) & 3);
      const f16* g = bm + (((size_t)(tap * 2 + batch) * CC + c) * L) + k0 + chl * 8;
      gl_lds16(g, Asm + R * 32 + (lane & 3) * 8);
    }
    for (int tau = tid; tau < 544; tau += 512) {
      int kk = tau / 17, ch = tau - kk * 17;
      int pbase = p0 + ch * 8;
      const f16* src = attnB + (size_t)(k0 + kk) * L + pbase;
      f16 v[8];
      if (pbase + 7 < L) {
        f16x8 vv = *(const f16x8*)src;
#pragma unroll
        for (int e = 0; e < 8; ++e) v[e] = vv[e];
      } else {
#pragma unroll
        for (int e = 0; e < 8; ++e) v[e] = (pbase + e < L) ? src[e] : (f16)0.f;
      }
#pragma unroll
      for (int e = 0; e < 8; ++e) {
        int pp = ch * 8 + e;
        Bt[pp * 40 + (((kk >> 3) ^ ((pp >> 3) & 3)) * 8) + (kk & 7)] = v[e];
      }
    }
    __syncthreads();
#pragma unroll
    for (int tap = 0; tap < 4; ++tap) {
      int dlt = (tap >> 1) * 64 + (tap & 1);
      f16x8 af[2], bf[2];
#pragma unroll
      for (int m = 0; m < 2; ++m) {
        int R = tap * 128 + wr * 32 + m * 16 + (lane & 15);
        int ph = (lane >> 4) ^ ((R >> 1) & 3);
        af[m] = *(const f16x8*)(Asm + R * 32 + ph * 8);
      }
#pragma unroll
      for (int n = 0; n < 2; ++n) {
        int pp = wc * 32 + n * 16 + (lane & 15) + dlt;
        int ph = (lane >> 4) ^ ((pp >> 3) & 3);
        bf[n] = *(const f16x8*)(Bt + pp * 40 + ph * 8);
      }
#pragma unroll
      for (int m = 0; m < 2; ++m)
#pragma unroll
        for (int n = 0; n < 2; ++n)
          acc[m][n] = __builtin_amdgcn_mfma_f32_16x16x32_f16(af[m], bf[n], acc[m][n], 0, 0, 0);
    }
  }
  int cb = wr * 32 + (lane >> 4) * 4;
  int pb = p0 + wc * 32 + (lane & 15);
#pragma unroll
  for (int m = 0; m < 2; ++m)
#pragma unroll
    for (int n = 0; n < 2; ++n)
#pragma unroll
      for (int r = 0; r < 4; ++r) {
        int c = cb + m * 16 + r;
        int p = pb + n * 16;
        part[(((size_t)ks * 2 + batch) * CC + c) * L + p] = acc[m][n][r];
      }
}

// ---------------- kernel 5b: sum K-split partials, scale, border mask --------------------
__global__ void k_agg_reduce(const float* __restrict__ part, float* __restrict__ out) {
  int idx = blockIdx.x * 256 + threadIdx.x;   // 2*128*4096
  int p = idx & (L - 1);
  float s = 0.f;
#pragma unroll
  for (int ks = 0; ks < 4; ++ks) s += part[(size_t)ks * (2 * CC * L) + idx];
  int u = p >> 6, v = p & 63;
  out[idx] = (u < 63 && v < 63) ? s * 0.25f : 0.f;
}

extern "C" void kernel_launch(void* const* d_in, const int* in_sizes, int n_in,
                              void* d_out, int out_size, void* d_ws, size_t ws_size,
                              hipStream_t stream) {
  const float* f = (const float*)d_in[0];
  const float* b = (const float*)d_in[1];
  const float* mask = (const float*)d_in[2];
  float* out = (float*)d_out;
  char* ws = (char*)d_ws;

  // Lifetimes: WN/FP(prep->gemm) -> T3 overwrites; S(gemm->fuse_stats) -> attn overwrites.
  f16* WN    = (f16*)(ws + 0);             // 18,874,368
  f16* FP    = (f16*)(ws + 18874368);      // 18,874,368
  float* T3  = (float*)(ws + 0);           // 134,217,728 (after gemm; over WN/FP)
  f16* S     = (f16*)(ws + 134217728);     // 67,108,864
  f16* attn  = (f16*)(ws + 134217728);     // aliases S (S dead after fuse_stats)
  f16* bm    = (f16*)(ws + 201326592);     // 8,388,608
  float* part= (float*)(ws + 209715200);   // 16,777,216
  float* pm  = (float*)(ws + 226492416);   // 8,388,608 (256 chunks x 8192 f32)
  float* pl  = (float*)(ws + 234881024);   // 8,388,608
  float* mmv = (float*)(ws + 243269632);   // 16,384
  float* Mq  = (float*)(ws + 243286016);   // 32,768
  float* Lq  = (float*)(ws + 243318784);   // 32,768

  k_prep_patches<<<dim3(2048), dim3(256), 0, stream>>>(f, b, WN, FP);
  k_prep_bm<<<dim3(16384), dim3(256), 0, stream>>>(b, bm);
  k_prep_mm<<<dim3(16), dim3(256), 0, stream>>>(mask, mmv);
  k_gemm_scores<<<dim3(32, 32, 2), dim3(256), 0, stream>>>(WN, FP, S);
  k_fuse_stats<<<dim3(2, 256, 2), dim3(256), 0, stream>>>(S, mmv, T3, pm, pl);
  k_fuse_stats_edge<<<dim3(256, 2), dim3(256), 0, stream>>>(S, mmv, T3, pm, pl);
  k_softmax_reduce<<<dim3(32), dim3(256), 0, stream>>>(pm, pl, Mq, Lq);
  k_attn<<<dim3(2, 128, 2), dim3(256), 0, stream>>>(T3, mmv, Mq, Lq, attn);
  k_agg<<<dim3(64, 4, 2), dim3(512), 0, stream>>>(attn, bm, part);
  k_agg_reduce<<<dim3(4096), dim3(256), 0, stream>>>(part, out);
}

// Round 6
// 379.891 us; speedup vs baseline: 1.3891x; 1.0365x over previous
//
#include <hip/hip_runtime.h>

#define L 4096
#define HH 64
#define CC 128
#define BB 2
#define KD 1152   // C*9

typedef _Float16 f16;
typedef _Float16 f16x8 __attribute__((ext_vector_type(8)));
typedef float f32x4 __attribute__((ext_vector_type(4)));

__device__ __forceinline__ void gl_lds16(const f16* g, f16* l) {
  __builtin_amdgcn_global_load_lds(
      (const __attribute__((address_space(1))) void*)g,
      (__attribute__((address_space(3))) void*)l, 16, 0, 0);
}

// sigma: involution converting row-major flat <-> col-major flat (64x64)
__device__ __forceinline__ int sigma_(int j) { return ((j & 63) << 6) | (j >> 6); }

// full 9-tap fused score from S (reference wrap semantics), scalar (edge columns)
__device__ float fuse9(const f16* __restrict__ Sb, int k, int j) {
  float acc = 0.f;
  int cK = sigma_(k), cQ = sigma_(j);
#pragma unroll
  for (int u = -1; u <= 1; ++u) {
    int a = cK + u, bq = cQ + u;
    if ((unsigned)a < L && (unsigned)bq < L) {
      int r = sigma_(a), c = sigma_(bq);
#pragma unroll
      for (int t = -1; t <= 1; ++t) {
        int rr = r + t, cc = c + t;
        if ((unsigned)rr < L && (unsigned)cc < L) acc += (float)Sb[(size_t)rr * L + cc];
      }
    }
  }
  return acc;
}

// ---------------- kernel 1a: im2col of f (FP) and normalized b (WN), f16 ----------------
__global__ __launch_bounds__(256) void k_prep_patches(
    const float* __restrict__ f, const float* __restrict__ b,
    f16* __restrict__ WN, f16* __restrict__ FP) {
  int wid = threadIdx.x >> 6;
  int lane = threadIdx.x & 63;
  int loc = blockIdx.x * 4 + wid;          // 0..8191 = batch*L + k
  int batch = loc >> 12;
  int k = loc & (L - 1);
  int ky = k >> 6, kx = k & 63;
  const float* bp = b + (size_t)batch * CC * L;
  const float* fp_ = f + (size_t)batch * CC * L;
  float bv[18], fv[18];
  float ss = 0.f;
#pragma unroll
  for (int it = 0; it < 18; ++it) {
    int d = it * 64 + lane;
    int c = d / 9;
    int r = d - c * 9;
    int yy = ky + (r / 3) - 1, xx = kx + (r % 3) - 1;
    bool ok = (yy >= 0 && yy < 64 && xx >= 0 && xx < 64);
    float vb = ok ? bp[(size_t)c * L + yy * 64 + xx] : 0.f;
    float vf = ok ? fp_[(size_t)c * L + yy * 64 + xx] : 0.f;
    bv[it] = vb; fv[it] = vf;
    ss += vb * vb;
  }
#pragma unroll
  for (int m = 32; m >= 1; m >>= 1) ss += __shfl_xor(ss, m, 64);
  float scale = 1.f / fmaxf(sqrtf(ss), 1e-4f);
  f16* wn = WN + (size_t)loc * KD;
  f16* fpo = FP + (size_t)loc * KD;
#pragma unroll
  for (int it = 0; it < 18; ++it) {
    int d = it * 64 + lane;
    wn[d] = (f16)(bv[it] * scale);
    fpo[d] = (f16)(fv[it]);
  }
}

// ---------------- kernel 1b: shifted+masked f16 copies of b for the 4 taps ---------------
__global__ void k_prep_bm(const float* __restrict__ b, f16* __restrict__ bm) {
  int idx = blockIdx.x * 256 + threadIdx.x;  // total 4*2*128*4096
  int k = idx & (L - 1);
  int c = (idx >> 12) & (CC - 1);
  int bt = idx >> 19;           // tap*2 + batch
  int batch = bt & 1;
  int tap = bt >> 1;
  int di = 1 - (tap >> 1), dj = 1 - (tap & 1);
  int ky = k >> 6, kx = k & 63;
  float v = 0.f;
  if (ky + di < 64 && kx + dj < 64)
    v = b[((size_t)batch * CC + c) * L + k + di * 64 + dj];
  bm[idx] = (f16)v;
}

// ---------------- kernel 1c: mask validity mm[k] -----------------------------------------
__global__ void k_prep_mm(const float* __restrict__ mask, float* __restrict__ mmv) {
  int k = blockIdx.x * 256 + threadIdx.x;
  if (k >= L) return;
  int ky = k >> 6, kx = k & 63;
  float s = 0.f;
  for (int i = 0; i < 3; ++i)
    for (int j = 0; j < 3; ++j) {
      int yy = ky + i - 1, xx = kx + j - 1;
      if (yy >= 0 && yy < 64 && xx >= 0 && xx < 64) s += mask[yy * 64 + xx];
    }
  mmv[k] = (s == 0.f) ? 1.f : 0.f;
}

// ---------------- kernel 2: scores GEMM, BK=64, XOR-swizzled LDS -------------------------
// S[k,q] = sum_d WN[k,d]*FP[q,d]; 128x128 tile, 4 waves (2x2), f16 MFMA 16x16x32.
// Swizzle: row = 8 chunks of 16B; LDS holds logical chunk (lane&7)^(row&7) at phys (lane&7).
__global__ __launch_bounds__(256) void k_gemm_scores(
    const f16* __restrict__ WN, const f16* __restrict__ FP, f16* __restrict__ S) {
  __shared__ f16 As[128 * 64];
  __shared__ f16 Bs[128 * 64];
  int qt = blockIdx.x, kt = blockIdx.y, batch = blockIdx.z;
  int tid = threadIdx.x, wid = tid >> 6, lane = tid & 63;
  int wr = wid >> 1, wc = wid & 1;
  const f16* Abase = WN + ((size_t)batch * L + kt * 128) * KD;
  const f16* Bbase = FP + ((size_t)batch * L + qt * 128) * KD;
  f32x4 acc[4][4] = {};
  int rA = wr * 64 + (lane & 15);
  int rB = wc * 64 + (lane & 15);
  for (int kk = 0; kk < KD; kk += 64) {
    __syncthreads();
#pragma unroll
    for (int i = 0; i < 4; ++i) {
      int chunk = (i * 4 + wid) * 64 + lane;        // 0..1023
      int row = chunk >> 3;                          // 0..127
      int lg = (lane & 7) ^ (row & 7);               // pre-swizzled source chunk
      gl_lds16(Abase + (size_t)row * KD + kk + lg * 8, As + chunk * 8);
      gl_lds16(Bbase + (size_t)row * KD + kk + lg * 8, Bs + chunk * 8);
    }
    __syncthreads();
#pragma unroll
    for (int half = 0; half < 2; ++half) {
      int cb = half * 4 + (lane >> 4);               // logical chunk within row
      f16x8 af[4], bf[4];
#pragma unroll
      for (int m = 0; m < 4; ++m) {
        int row = rA + m * 16;
        af[m] = *(const f16x8*)(As + row * 64 + ((cb ^ (row & 7)) * 8));
      }
#pragma unroll
      for (int n = 0; n < 4; ++n) {
        int row = rB + n * 16;
        bf[n] = *(const f16x8*)(Bs + row * 64 + ((cb ^ (row & 7)) * 8));
      }
#pragma unroll
      for (int m = 0; m < 4; ++m)
#pragma unroll
        for (int n = 0; n < 4; ++n)
          acc[m][n] = __builtin_amdgcn_mfma_f32_16x16x32_f16(af[m], bf[n], acc[m][n], 0, 0, 0);
    }
  }
  f16* Srow = S + (size_t)batch * L * L;
  int kbase = kt * 128 + wr * 64 + (lane >> 4) * 4;
  int qbase = qt * 128 + wc * 64 + (lane & 15);
#pragma unroll
  for (int m = 0; m < 4; ++m)
#pragma unroll
    for (int r = 0; r < 4; ++r) {
      f16* dst = Srow + (size_t)(kbase + m * 16 + r) * L + qbase;
#pragma unroll
      for (int n = 0; n < 4; ++n) dst[n * 16] = (f16)acc[m][n][r];
    }
}

// ---------------- kernel 3: fused stencil -> T3 + online softmax partials ----------------
__global__ __launch_bounds__(256) void k_fuse_stats(
    const f16* __restrict__ S, const float* __restrict__ mmv,
    float* __restrict__ T3, float* __restrict__ pm, float* __restrict__ pl) {
  int tid = threadIdx.x;
  if (tid >= 247) return;
  int jc = blockIdx.x, kc = blockIdx.y, batch = blockIdx.z;
  int g = jc * 247 + tid;                  // 0..493
  int q0 = 72 + g * 8;                     // aligned, fully interior group
  const f16* Sb = S + (size_t)batch * L * L;
  float* Tb = T3 + (size_t)batch * L * L;
  float m8[8], l8[8];
#pragma unroll
  for (int e = 0; e < 8; ++e) { m8[e] = -3.0e38f; l8[e] = 0.f; }
  int cnt = 0;
  int k0 = kc * 16;
  for (int kk = 0; kk < 16; ++kk) {
    int k = k0 + kk;
    if (mmv[k] == 0.f) { ++cnt; continue; }
    float acc[8] = {0.f, 0.f, 0.f, 0.f, 0.f, 0.f, 0.f, 0.f};
    int cK = sigma_(k);
#pragma unroll
    for (int u = -1; u <= 1; ++u) {
      int a = cK + u;
      if ((unsigned)a >= L) continue;
      int r = sigma_(a);                   // = k + 64u for interior k
      const f16* cb = Sb + (size_t)r * L + (q0 + 64 * u);
      {
        f16x8 v = *(const f16x8*)cb;
#pragma unroll
        for (int e = 0; e < 8; ++e) acc[e] += (float)v[e];
      }
      if (r >= 1) {
        const f16* rm = cb - L;
        f16x8 v = *(const f16x8*)rm;
        acc[0] += (float)rm[-1];
#pragma unroll
        for (int e = 1; e < 8; ++e) acc[e] += (float)v[e - 1];
      }
      if (r <= L - 2) {
        const f16* rp = cb + L;
        f16x8 v = *(const f16x8*)rp;
#pragma unroll
        for (int e = 0; e < 7; ++e) acc[e] += (float)v[e + 1];
        acc[7] += (float)rp[8];
      }
    }
#pragma unroll
    for (int e = 0; e < 8; ++e) acc[e] *= 10.f;
    float* trow = Tb + (size_t)k * L + q0;
    *(f32x4*)trow = *(f32x4*)&acc[0];
    *(f32x4*)(trow + 4) = *(f32x4*)&acc[4];
#pragma unroll
    for (int e = 0; e < 8; ++e) {
      float nm = fmaxf(m8[e], acc[e]);
      l8[e] = l8[e] * __expf(m8[e] - nm) + __expf(acc[e] - nm);
      m8[e] = nm;
    }
  }
  float fc = (float)cnt;
  float om[8], ol[8];
#pragma unroll
  for (int e = 0; e < 8; ++e) {
    float nm = fmaxf(m8[e], 0.f);
    ol[e] = l8[e] * __expf(m8[e] - nm) + fc * __expf(-nm);
    om[e] = nm;
  }
  float* pmp = pm + (size_t)kc * (BB * L) + (size_t)batch * L + q0;
  float* plp = pl + (size_t)kc * (BB * L) + (size_t)batch * L + q0;
  *(f32x4*)pmp = *(f32x4*)&om[0]; *(f32x4*)(pmp + 4) = *(f32x4*)&om[4];
  *(f32x4*)plp = *(f32x4*)&ol[0]; *(f32x4*)(plp + 4) = *(f32x4*)&ol[4];
}

// ---------------- kernel 3e: edge q columns (144 cols), scalar fuse9 ---------------------
__global__ __launch_bounds__(256) void k_fuse_stats_edge(
    const f16* __restrict__ S, const float* __restrict__ mmv,
    float* __restrict__ T3, float* __restrict__ pm, float* __restrict__ pl) {
  int tid = threadIdx.x;
  if (tid >= 144) return;
  int q = (tid < 72) ? tid : (4024 + tid - 72);
  int kc = blockIdx.x, batch = blockIdx.y;
  const f16* Sb = S + (size_t)batch * L * L;
  float* Tb = T3 + (size_t)batch * L * L;
  float m = -3.0e38f, l = 0.f;
  int cnt = 0;
  int k0 = kc * 16;
  for (int kk = 0; kk < 16; ++kk) {
    int k = k0 + kk;
    if (mmv[k] == 0.f) { ++cnt; continue; }
    float logit = 10.f * fuse9(Sb, k, q);
    Tb[(size_t)k * L + q] = logit;
    float nm = fmaxf(m, logit);
    l = l * __expf(m - nm) + __expf(logit - nm);
    m = nm;
  }
  float nm = fmaxf(m, 0.f);
  l = l * __expf(m - nm) + (float)cnt * __expf(-nm);
  pm[(size_t)kc * (BB * L) + (size_t)batch * L + q] = nm;
  pl[(size_t)kc * (BB * L) + (size_t)batch * L + q] = l;
}

// ---------------- kernel 3b: combine partials; store M and 1/L ---------------------------
__global__ void k_softmax_reduce(const float* __restrict__ pm, const float* __restrict__ pl,
                                 float* __restrict__ Mq, float* __restrict__ invLq) {
  int qi = blockIdx.x * 256 + threadIdx.x;
  if (qi >= BB * L) return;
  float M = -3.0e38f;
  for (int i = 0; i < 256; ++i) M = fmaxf(M, pm[(size_t)i * (BB * L) + qi]);
  float Ls = 0.f;
  for (int i = 0; i < 256; ++i) Ls += pl[(size_t)i * (BB * L) + qi] * __expf(pm[(size_t)i * (BB * L) + qi] - M);
  Mq[qi] = M;
  invLq[qi] = 1.f / Ls;
}

// ---------------- kernel 5: aggregation with fused softmax-exp B-staging -----------------
// part[ks][batch][c][p] = sum_{k in chunk} sum_tap bm[tap][batch][c][k] * attn(k, p+dlt)
// attn(k,q) = mmv[k] ? exp(T3[k][q]-M[q])*invL[q] : 0, computed during Bt staging.
__global__ __launch_bounds__(512) void k_agg(
    const float* __restrict__ T3, const float* __restrict__ mmv,
    const float* __restrict__ Mq, const float* __restrict__ invLq,
    const f16* __restrict__ bm, float* __restrict__ part) {
  __shared__ f16 Asm[512 * 32];   // [R=tap*128+c][32kk], chunk-swizzled: phys = log ^ ((R>>1)&3)
  __shared__ f16 Bt[136 * 40];    // [pp][kk], kk-chunk swizzled: phys = log ^ ((pp>>3)&3)
  int pt = blockIdx.x, ks = blockIdx.y, batch = blockIdx.z;
  int p0 = pt * 64;
  int tid = threadIdx.x, wid = tid >> 6, lane = tid & 63;
  int wr = wid >> 1, wc = wid & 1;
  const float* Tb = T3 + (size_t)batch * L * L;
  const float* mq0 = Mq + (size_t)batch * L;
  const float* il0 = invLq + (size_t)batch * L;
  f32x4 acc[2][2] = {};
  int kend = ks * 1024 + 1024;
  for (int k0 = ks * 1024; k0 < kend; k0 += 32) {
    __syncthreads();
#pragma unroll
    for (int i = 0; i < 4; ++i) {
      int R = wid * 64 + i * 16 + (lane >> 2);
      int tap = R >> 7, c = R & 127;
      int chl = (lane & 3) ^ ((R >> 1) & 3);
      const f16* g = bm + (((size_t)(tap * 2 + batch) * CC + c) * L) + k0 + chl * 8;
      gl_lds16(g, Asm + R * 32 + (lane & 3) * 8);
    }
    // B staging: Bt[pp][kk] = attn(k0+kk, p0+pp) with exp fused, 544 tasks
    for (int tau = tid; tau < 544; tau += 512) {
      int kk = tau / 17, ch = tau - kk * 17;
      int k = k0 + kk;
      int pbase = p0 + ch * 8;
      f16 v[8];
      if (mmv[k] != 0.f) {
        const float* trow = Tb + (size_t)k * L + pbase;
        if (pbase + 7 < L) {
          f32x4 t0 = *(const f32x4*)trow;
          f32x4 t1 = *(const f32x4*)(trow + 4);
          f32x4 m0 = *(const f32x4*)(mq0 + pbase);
          f32x4 m1 = *(const f32x4*)(mq0 + pbase + 4);
          f32x4 i0 = *(const f32x4*)(il0 + pbase);
          f32x4 i1 = *(const f32x4*)(il0 + pbase + 4);
#pragma unroll
          for (int e = 0; e < 4; ++e) v[e] = (f16)(__expf(t0[e] - m0[e]) * i0[e]);
#pragma unroll
          for (int e = 0; e < 4; ++e) v[4 + e] = (f16)(__expf(t1[e] - m1[e]) * i1[e]);
        } else {
#pragma unroll
          for (int e = 0; e < 8; ++e) {
            int q = pbase + e;
            v[e] = (q < L) ? (f16)(__expf(trow[e] - mq0[q]) * il0[q]) : (f16)0.f;
          }
        }
      } else {
#pragma unroll
        for (int e = 0; e < 8; ++e) v[e] = (f16)0.f;
      }
#pragma unroll
      for (int e = 0; e < 8; ++e) {
        int pp = ch * 8 + e;
        Bt[pp * 40 + (((kk >> 3) ^ ((pp >> 3) & 3)) * 8) + (kk & 7)] = v[e];
      }
    }
    __syncthreads();
#pragma unroll
    for (int tap = 0; tap < 4; ++tap) {
      int dlt = (tap >> 1) * 64 + (tap & 1);
      f16x8 af[2], bf[2];
#pragma unroll
      for (int m = 0; m < 2; ++m) {
        int R = tap * 128 + wr * 32 + m * 16 + (lane & 15);
        int ph = (lane >> 4) ^ ((R >> 1) & 3);
        af[m] = *(const f16x8*)(Asm + R * 32 + ph * 8);
      }
#pragma unroll
      for (int n = 0; n < 2; ++n) {
        int pp = wc * 32 + n * 16 + (lane & 15) + dlt;
        int ph = (lane >> 4) ^ ((pp >> 3) & 3);
        bf[n] = *(const f16x8*)(Bt + pp * 40 + ph * 8);
      }
#pragma unroll
      for (int m = 0; m < 2; ++m)
#pragma unroll
        for (int n = 0; n < 2; ++n)
          acc[m][n] = __builtin_amdgcn_mfma_f32_16x16x32_f16(af[m], bf[n], acc[m][n], 0, 0, 0);
    }
  }
  int cb = wr * 32 + (lane >> 4) * 4;
  int pb = p0 + wc * 32 + (lane & 15);
#pragma unroll
  for (int m = 0; m < 2; ++m)
#pragma unroll
    for (int n = 0; n < 2; ++n)
#pragma unroll
      for (int r = 0; r < 4; ++r) {
        int c = cb + m * 16 + r;
        int p = pb + n * 16;
        part[(((size_t)ks * 2 + batch) * CC + c) * L + p] = acc[m][n][r];
      }
}

// ---------------- kernel 5b: sum K-split partials, scale, border mask --------------------
__global__ void k_agg_reduce(const float* __restrict__ part, float* __restrict__ out) {
  int idx = blockIdx.x * 256 + threadIdx.x;   // 2*128*4096
  int p = idx & (L - 1);
  float s = 0.f;
#pragma unroll
  for (int ks = 0; ks < 4; ++ks) s += part[(size_t)ks * (2 * CC * L) + idx];
  int u = p >> 6, v = p & 63;
  out[idx] = (u < 63 && v < 63) ? s * 0.25f : 0.f;
}

extern "C" void kernel_launch(void* const* d_in, const int* in_sizes, int n_in,
                              void* d_out, int out_size, void* d_ws, size_t ws_size,
                              hipStream_t stream) {
  const float* f = (const float*)d_in[0];
  const float* b = (const float*)d_in[1];
  const float* mask = (const float*)d_in[2];
  float* out = (float*)d_out;
  char* ws = (char*)d_ws;

  // Lifetimes: WN/FP(prep->gemm) -> T3 overwrites; S(gemm->fuse_stats); T3 read by agg.
  f16* WN    = (f16*)(ws + 0);             // 18,874,368
  f16* FP    = (f16*)(ws + 18874368);      // 18,874,368
  float* T3  = (float*)(ws + 0);           // 134,217,728 (after gemm; over WN/FP)
  f16* S     = (f16*)(ws + 134217728);     // 67,108,864
  f16* bm    = (f16*)(ws + 201326592);     // 8,388,608
  float* part= (float*)(ws + 209715200);   // 16,777,216
  float* pm  = (float*)(ws + 226492416);   // 8,388,608 (256 chunks x 8192 f32)
  float* pl  = (float*)(ws + 234881024);   // 8,388,608
  float* mmv = (float*)(ws + 243269632);   // 16,384
  float* Mq  = (float*)(ws + 243286016);   // 32,768
  float* iLq = (float*)(ws + 243318784);   // 32,768

  k_prep_patches<<<dim3(2048), dim3(256), 0, stream>>>(f, b, WN, FP);
  k_prep_bm<<<dim3(16384), dim3(256), 0, stream>>>(b, bm);
  k_prep_mm<<<dim3(16), dim3(256), 0, stream>>>(mask, mmv);
  k_gemm_scores<<<dim3(32, 32, 2), dim3(256), 0, stream>>>(WN, FP, S);
  k_fuse_stats<<<dim3(2, 256, 2), dim3(256), 0, stream>>>(S, mmv, T3, pm, pl);
  k_fuse_stats_edge<<<dim3(256, 2), dim3(256), 0, stream>>>(S, mmv, T3, pm, pl);
  k_softmax_reduce<<<dim3(32), dim3(256), 0, stream>>>(pm, pl, Mq, iLq);
  k_agg<<<dim3(64, 4, 2), dim3(512), 0, stream>>>(T3, mmv, Mq, iLq, bm, part);
  k_agg_reduce<<<dim3(4096), dim3(256), 0, stream>>>(part, out);
}

// Round 7
// 377.174 us; speedup vs baseline: 1.3991x; 1.0072x over previous
//
#include <hip/hip_runtime.h>

#define L 4096
#define HH 64
#define CC 128
#define BB 2

typedef _Float16 f16;
typedef _Float16 f16x8 __attribute__((ext_vector_type(8)));
typedef float f32x4 __attribute__((ext_vector_type(4)));

__device__ __forceinline__ void gl_lds16(const f16* g, f16* l) {
  __builtin_amdgcn_global_load_lds(
      (const __attribute__((address_space(1))) void*)g,
      (__attribute__((address_space(3))) void*)l, 16, 0, 0);
}

// sigma: involution converting row-major flat <-> col-major flat (64x64)
__device__ __forceinline__ int sigma_(int j) { return ((j & 63) << 6) | (j >> 6); }

// full 9-tap fused score from S (reference wrap semantics), scalar (edge columns)
__device__ float fuse9(const f16* __restrict__ Sb, int k, int j) {
  float acc = 0.f;
  int cK = sigma_(k), cQ = sigma_(j);
#pragma unroll
  for (int u = -1; u <= 1; ++u) {
    int a = cK + u, bq = cQ + u;
    if ((unsigned)a < L && (unsigned)bq < L) {
      int r = sigma_(a), c = sigma_(bq);
#pragma unroll
      for (int t = -1; t <= 1; ++t) {
        int rr = r + t, cc = c + t;
        if ((unsigned)rr < L && (unsigned)cc < L) acc += (float)Sb[(size_t)rr * L + cc];
      }
    }
  }
  return acc;
}

// ---------------- kernel 0a: repack [c][u] f32 -> [u][c] f16 (b and f), zero zeropage ----
__global__ __launch_bounds__(256) void k_repack(
    const float* __restrict__ b, const float* __restrict__ f,
    f16* __restrict__ bT, f16* __restrict__ fT, f16* __restrict__ zp) {
  __shared__ float tile[128][65];
  int u0 = blockIdx.x * 64;
  int z = blockIdx.y;            // batch*2 + tensor
  int batch = z >> 1;
  const float* src = ((z & 1) ? f : b) + (size_t)batch * CC * L;
  f16* dst = ((z & 1) ? fT : bT) + (size_t)batch * L * CC;
  int tid = threadIdx.x;
  if (blockIdx.x == 0 && z == 0 && tid < 32) zp[tid] = (f16)0.f;
#pragma unroll
  for (int i = 0; i < 32; ++i) {
    int idx = i * 256 + tid;
    int c = idx >> 6, ux = idx & 63;
    tile[c][ux] = src[(size_t)c * L + u0 + ux];
  }
  __syncthreads();
#pragma unroll
  for (int j = 0; j < 4; ++j) {
    int t2 = j * 256 + tid;
    int u = t2 >> 4, ch = t2 & 15;
    f16x8 v;
#pragma unroll
    for (int e = 0; e < 8; ++e) v[e] = (f16)tile[ch * 8 + e][u];
    *(f16x8*)(dst + (size_t)(u0 + u) * CC + ch * 8) = v;
  }
}

// ---------------- kernel 0b: ssq[batch][u] = sum_c b[c][u]^2 -----------------------------
__global__ __launch_bounds__(256) void k_ssq(const float* __restrict__ b, float* __restrict__ ssq) {
  int u = blockIdx.x * 256 + threadIdx.x;
  int batch = blockIdx.y;
  const float* bp = b + (size_t)batch * CC * L + u;
  float s = 0.f;
#pragma unroll 4
  for (int c = 0; c < CC; ++c) { float v = bp[(size_t)c * L]; s += v * v; }
  ssq[batch * L + u] = s;
}

// ---------------- kernel 0c: inv_n[batch][k] = 1/max(sqrt(sum_{r valid} ssq),1e-4) -------
__global__ void k_norm(const float* __restrict__ ssq, float* __restrict__ inv_n) {
  int gi = blockIdx.x * 256 + threadIdx.x;
  if (gi >= BB * L) return;
  int batch = gi >> 12, k = gi & (L - 1);
  int ky = k >> 6, kx = k & 63;
  float s = 0.f;
#pragma unroll
  for (int dy = -1; dy <= 1; ++dy)
#pragma unroll
    for (int dx = -1; dx <= 1; ++dx) {
      if ((unsigned)(ky + dy) < 64 && (unsigned)(kx + dx) < 64)
        s += ssq[batch * L + k + dy * 64 + dx];
    }
  inv_n[gi] = 1.f / fmaxf(sqrtf(s), 1e-4f);
}

// ---------------- kernel 1b: shifted+masked f16 copies of b (vectorized) -----------------
__global__ __launch_bounds__(256) void k_prep_bm(const float* __restrict__ b, f16* __restrict__ bm) {
  int idx = blockIdx.x * 256 + threadIdx.x;  // x8 elements
  int e8 = idx * 8;
  int k0 = e8 & (L - 1);
  int c = (e8 >> 12) & (CC - 1);
  int bt = e8 >> 19;            // tap*2 + batch
  int batch = bt & 1;
  int tap = bt >> 1;
  int di = 1 - (tap >> 1), dj = 1 - (tap & 1);
  int ky = k0 >> 6, kx0 = k0 & 63;
  const float* src = b + ((size_t)batch * CC + c) * L + k0 + di * 64 + dj;
  bool rowok = (ky + di) < 64;
  f16x8 v;
#pragma unroll
  for (int e = 0; e < 8; ++e) {
    float x = (rowok && (kx0 + e + dj) < 64) ? src[e] : 0.f;
    v[e] = (f16)x;
  }
  *(f16x8*)(bm + (size_t)e8) = v;
}

// ---------------- kernel 1c: mask validity mm[k] -----------------------------------------
__global__ void k_prep_mm(const float* __restrict__ mask, float* __restrict__ mmv) {
  int k = blockIdx.x * 256 + threadIdx.x;
  if (k >= L) return;
  int ky = k >> 6, kx = k & 63;
  float s = 0.f;
  for (int i = 0; i < 3; ++i)
    for (int j = 0; j < 3; ++j) {
      int yy = ky + i - 1, xx = kx + j - 1;
      if (yy >= 0 && yy < 64 && xx >= 0 && xx < 64) s += mask[yy * 64 + xx];
    }
  mmv[k] = (s == 0.f) ? 1.f : 0.f;
}

// ---------------- kernel 2: implicit-patch scores GEMM -----------------------------------
// S[k,q] = inv_n[k] * sum_{r in 3x3} [valid] <b[:,k+r], f[:,q+r]>
// 128x128 tile, 4 waves (2x2), f16 MFMA 16x16x32; 18 steps = 9 shifts x 2 c-halves.
// LDS XOR-swizzled (pre-swizzled source chunks); invalid rows stage from zeropage.
__global__ __launch_bounds__(256) void k_gemm_scores(
    const f16* __restrict__ bT, const f16* __restrict__ fT,
    const float* __restrict__ inv_n, const f16* __restrict__ zp,
    f16* __restrict__ S) {
  __shared__ f16 As[128 * 64];
  __shared__ f16 Bs[128 * 64];
  int qt = blockIdx.x, kt = blockIdx.y, batch = blockIdx.z;
  int tid = threadIdx.x, wid = tid >> 6, lane = tid & 63;
  int wr = wid >> 1, wc = wid & 1;
  const f16* A0 = bT + (size_t)batch * L * CC;
  const f16* B0 = fT + (size_t)batch * L * CC;
  f32x4 acc[4][4] = {};
  int rA = wr * 64 + (lane & 15);
  int rB = wc * 64 + (lane & 15);
  for (int t = 0; t < 18; ++t) {
    int r = t >> 1, half = t & 1;
    int dy = r / 3 - 1, dx = r - (r / 3) * 3 - 1;
    int dlt = dy * 64 + dx;
    __syncthreads();
#pragma unroll
    for (int i = 0; i < 4; ++i) {
      int chunk = (i * 4 + wid) * 64 + lane;        // 0..1023
      int row = chunk >> 3;                          // 0..127
      int lg = (lane & 7) ^ (row & 7);               // pre-swizzled source chunk
      int off = half * 64 + lg * 8;
      {
        int k = kt * 128 + row;
        bool va = ((unsigned)((k >> 6) + dy) < 64) && ((unsigned)((k & 63) + dx) < 64);
        const f16* ga = va ? (A0 + (size_t)(k + dlt) * CC + off) : zp;
        gl_lds16(ga, As + chunk * 8);
      }
      {
        int q = qt * 128 + row;
        bool vb = ((unsigned)((q >> 6) + dy) < 64) && ((unsigned)((q & 63) + dx) < 64);
        const f16* gb = vb ? (B0 + (size_t)(q + dlt) * CC + off) : zp;
        gl_lds16(gb, Bs + chunk * 8);
      }
    }
    __syncthreads();
#pragma unroll
    for (int h2 = 0; h2 < 2; ++h2) {
      int cb = h2 * 4 + (lane >> 4);                 // logical chunk within row
      f16x8 af[4], bf[4];
#pragma unroll
      for (int m = 0; m < 4; ++m) {
        int row = rA + m * 16;
        af[m] = *(const f16x8*)(As + row * 64 + ((cb ^ (row & 7)) * 8));
      }
#pragma unroll
      for (int n = 0; n < 4; ++n) {
        int row = rB + n * 16;
        bf[n] = *(const f16x8*)(Bs + row * 64 + ((cb ^ (row & 7)) * 8));
      }
#pragma unroll
      for (int m = 0; m < 4; ++m)
#pragma unroll
        for (int n = 0; n < 4; ++n)
          acc[m][n] = __builtin_amdgcn_mfma_f32_16x16x32_f16(af[m], bf[n], acc[m][n], 0, 0, 0);
    }
  }
  f16* Srow = S + (size_t)batch * L * L;
  int kbase = kt * 128 + wr * 64 + (lane >> 4) * 4;
  int qbase = qt * 128 + wc * 64 + (lane & 15);
#pragma unroll
  for (int m = 0; m < 4; ++m) {
    f32x4 invv = *(const f32x4*)(inv_n + (size_t)batch * L + kbase + m * 16);
#pragma unroll
    for (int r = 0; r < 4; ++r) {
      f16* dst = Srow + (size_t)(kbase + m * 16 + r) * L + qbase;
#pragma unroll
      for (int n = 0; n < 4; ++n) dst[n * 16] = (f16)(acc[m][n][r] * invv[r]);
    }
  }
}

// ---------------- kernel 3: fused stencil -> T3 + online softmax partials ----------------
__global__ __launch_bounds__(256) void k_fuse_stats(
    const f16* __restrict__ S, const float* __restrict__ mmv,
    float* __restrict__ T3, float* __restrict__ pm, float* __restrict__ pl) {
  int tid = threadIdx.x;
  if (tid >= 247) return;
  int jc = blockIdx.x, kc = blockIdx.y, batch = blockIdx.z;
  int g = jc * 247 + tid;                  // 0..493
  int q0 = 72 + g * 8;                     // aligned, fully interior group
  const f16* Sb = S + (size_t)batch * L * L;
  float* Tb = T3 + (size_t)batch * L * L;
  float m8[8], l8[8];
#pragma unroll
  for (int e = 0; e < 8; ++e) { m8[e] = -3.0e38f; l8[e] = 0.f; }
  int cnt = 0;
  int k0 = kc * 16;
  for (int kk = 0; kk < 16; ++kk) {
    int k = k0 + kk;
    if (mmv[k] == 0.f) { ++cnt; continue; }
    float acc[8] = {0.f, 0.f, 0.f, 0.f, 0.f, 0.f, 0.f, 0.f};
    int cK = sigma_(k);
#pragma unroll
    for (int u = -1; u <= 1; ++u) {
      int a = cK + u;
      if ((unsigned)a >= L) continue;
      int r = sigma_(a);                   // = k + 64u for interior k
      const f16* cb = Sb + (size_t)r * L + (q0 + 64 * u);
      {
        f16x8 v = *(const f16x8*)cb;
#pragma unroll
        for (int e = 0; e < 8; ++e) acc[e] += (float)v[e];
      }
      if (r >= 1) {
        const f16* rm = cb - L;
        f16x8 v = *(const f16x8*)rm;
        acc[0] += (float)rm[-1];
#pragma unroll
        for (int e = 1; e < 8; ++e) acc[e] += (float)v[e - 1];
      }
      if (r <= L - 2) {
        const f16* rp = cb + L;
        f16x8 v = *(const f16x8*)rp;
#pragma unroll
        for (int e = 0; e < 7; ++e) acc[e] += (float)v[e + 1];
        acc[7] += (float)rp[8];
      }
    }
#pragma unroll
    for (int e = 0; e < 8; ++e) acc[e] *= 10.f;
    float* trow = Tb + (size_t)k * L + q0;
    *(f32x4*)trow = *(f32x4*)&acc[0];
    *(f32x4*)(trow + 4) = *(f32x4*)&acc[4];
#pragma unroll
    for (int e = 0; e < 8; ++e) {
      float nm = fmaxf(m8[e], acc[e]);
      l8[e] = l8[e] * __expf(m8[e] - nm) + __expf(acc[e] - nm);
      m8[e] = nm;
    }
  }
  float fc = (float)cnt;
  float om[8], ol[8];
#pragma unroll
  for (int e = 0; e < 8; ++e) {
    float nm = fmaxf(m8[e], 0.f);
    ol[e] = l8[e] * __expf(m8[e] - nm) + fc * __expf(-nm);
    om[e] = nm;
  }
  float* pmp = pm + (size_t)kc * (BB * L) + (size_t)batch * L + q0;
  float* plp = pl + (size_t)kc * (BB * L) + (size_t)batch * L + q0;
  *(f32x4*)pmp = *(f32x4*)&om[0]; *(f32x4*)(pmp + 4) = *(f32x4*)&om[4];
  *(f32x4*)plp = *(f32x4*)&ol[0]; *(f32x4*)(plp + 4) = *(f32x4*)&ol[4];
}

// ---------------- kernel 3e: edge q columns (144 cols), scalar fuse9 ---------------------
__global__ __launch_bounds__(256) void k_fuse_stats_edge(
    const f16* __restrict__ S, const float* __restrict__ mmv,
    float* __restrict__ T3, float* __restrict__ pm, float* __restrict__ pl) {
  int tid = threadIdx.x;
  if (tid >= 144) return;
  int q = (tid < 72) ? tid : (4024 + tid - 72);
  int kc = blockIdx.x, batch = blockIdx.y;
  const f16* Sb = S + (size_t)batch * L * L;
  float* Tb = T3 + (size_t)batch * L * L;
  float m = -3.0e38f, l = 0.f;
  int cnt = 0;
  int k0 = kc * 16;
  for (int kk = 0; kk < 16; ++kk) {
    int k = k0 + kk;
    if (mmv[k] == 0.f) { ++cnt; continue; }
    float logit = 10.f * fuse9(Sb, k, q);
    Tb[(size_t)k * L + q] = logit;
    float nm = fmaxf(m, logit);
    l = l * __expf(m - nm) + __expf(logit - nm);
    m = nm;
  }
  float nm = fmaxf(m, 0.f);
  l = l * __expf(m - nm) + (float)cnt * __expf(-nm);
  pm[(size_t)kc * (BB * L) + (size_t)batch * L + q] = nm;
  pl[(size_t)kc * (BB * L) + (size_t)batch * L + q] = l;
}

// ---------------- kernel 3b: combine partials; store M and 1/L ---------------------------
__global__ void k_softmax_reduce(const float* __restrict__ pm, const float* __restrict__ pl,
                                 float* __restrict__ Mq, float* __restrict__ invLq) {
  int qi = blockIdx.x * 256 + threadIdx.x;
  if (qi >= BB * L) return;
  float M = -3.0e38f;
  for (int i = 0; i < 256; ++i) M = fmaxf(M, pm[(size_t)i * (BB * L) + qi]);
  float Ls = 0.f;
  for (int i = 0; i < 256; ++i) Ls += pl[(size_t)i * (BB * L) + qi] * __expf(pm[(size_t)i * (BB * L) + qi] - M);
  Mq[qi] = M;
  invLq[qi] = 1.f / Ls;
}

// ---------------- kernel 5: aggregation with fused softmax-exp B-staging -----------------
__global__ __launch_bounds__(512) void k_agg(
    const float* __restrict__ T3, const float* __restrict__ mmv,
    const float* __restrict__ Mq, const float* __restrict__ invLq,
    const f16* __restrict__ bm, float* __restrict__ part) {
  __shared__ f16 Asm[512 * 32];   // [R=tap*128+c][32kk], chunk-swizzled: phys = log ^ ((R>>1)&3)
  __shared__ f16 Bt[136 * 40];    // [pp][kk], kk-chunk swizzled: phys = log ^ ((pp>>3)&3)
  int pt = blockIdx.x, ks = blockIdx.y, batch = blockIdx.z;
  int p0 = pt * 64;
  int tid = threadIdx.x, wid = tid >> 6, lane = tid & 63;
  int wr = wid >> 1, wc = wid & 1;
  const float* Tb = T3 + (size_t)batch * L * L;
  const float* mq0 = Mq + (size_t)batch * L;
  const float* il0 = invLq + (size_t)batch * L;
  f32x4 acc[2][2] = {};
  int kend = ks * 1024 + 1024;
  for (int k0 = ks * 1024; k0 < kend; k0 += 32) {
    __syncthreads();
#pragma unroll
    for (int i = 0; i < 4; ++i) {
      int R = wid * 64 + i * 16 + (lane >> 2);
      int tap = R >> 7, c = R & 127;
      int chl = (lane & 3) ^ ((R >> 1) & 3);
      const f16* g = bm + (((size_t)(tap * 2 + batch) * CC + c) * L) + k0 + chl * 8;
      gl_lds16(g, Asm + R * 32 + (lane & 3) * 8);
    }
    // B staging: Bt[pp][kk] = attn(k0+kk, p0+pp) with exp fused, 544 tasks
    for (int tau = tid; tau < 544; tau += 512) {
      int kk = tau / 17, ch = tau - kk * 17;
      int k = k0 + kk;
      int pbase = p0 + ch * 8;
      f16 v[8];
      if (mmv[k] != 0.f) {
        const float* trow = Tb + (size_t)k * L + pbase;
        if (pbase + 7 < L) {
          f32x4 t0 = *(const f32x4*)trow;
          f32x4 t1 = *(const f32x4*)(trow + 4);
          f32x4 m0 = *(const f32x4*)(mq0 + pbase);
          f32x4 m1 = *(const f32x4*)(mq0 + pbase + 4);
          f32x4 i0 = *(const f32x4*)(il0 + pbase);
          f32x4 i1 = *(const f32x4*)(il0 + pbase + 4);
#pragma unroll
          for (int e = 0; e < 4; ++e) v[e] = (f16)(__expf(t0[e] - m0[e]) * i0[e]);
#pragma unroll
          for (int e = 0; e < 4; ++e) v[4 + e] = (f16)(__expf(t1[e] - m1[e]) * i1[e]);
        } else {
#pragma unroll
          for (int e = 0; e < 8; ++e) {
            int q = pbase + e;
            v[e] = (q < L) ? (f16)(__expf(trow[e] - mq0[q]) * il0[q]) : (f16)0.f;
          }
        }
      } else {
#pragma unroll
        for (int e = 0; e < 8; ++e) v[e] = (f16)0.f;
      }
#pragma unroll
      for (int e = 0; e < 8; ++e) {
        int pp = ch * 8 + e;
        Bt[pp * 40 + (((kk >> 3) ^ ((pp >> 3) & 3)) * 8) + (kk & 7)] = v[e];
      }
    }
    __syncthreads();
#pragma unroll
    for (int tap = 0; tap < 4; ++tap) {
      int dlt = (tap >> 1) * 64 + (tap & 1);
      f16x8 af[2], bf[2];
#pragma unroll
      for (int m = 0; m < 2; ++m) {
        int R = tap * 128 + wr * 32 + m * 16 + (lane & 15);
        int ph = (lane >> 4) ^ ((R >> 1) & 3);
        af[m] = *(const f16x8*)(Asm + R * 32 + ph * 8);
      }
#pragma unroll
      for (int n = 0; n < 2; ++n) {
        int pp = wc * 32 + n * 16 + (lane & 15) + dlt;
        int ph = (lane >> 4) ^ ((pp >> 3) & 3);
        bf[n] = *(const f16x8*)(Bt + pp * 40 + ph * 8);
      }
#pragma unroll
      for (int m = 0; m < 2; ++m)
#pragma unroll
        for (int n = 0; n < 2; ++n)
          acc[m][n] = __builtin_amdgcn_mfma_f32_16x16x32_f16(af[m], bf[n], acc[m][n], 0, 0, 0);
    }
  }
  int cb = wr * 32 + (lane >> 4) * 4;
  int pb = p0 + wc * 32 + (lane & 15);
#pragma unroll
  for (int m = 0; m < 2; ++m)
#pragma unroll
    for (int n = 0; n < 2; ++n)
#pragma unroll
      for (int r = 0; r < 4; ++r) {
        int c = cb + m * 16 + r;
        int p = pb + n * 16;
        part[(((size_t)ks * 2 + batch) * CC + c) * L + p] = acc[m][n][r];
      }
}

// ---------------- kernel 5b: sum K-split partials, scale, border mask (vectorized) -------
__global__ __launch_bounds__(256) void k_agg_reduce(const float* __restrict__ part, float* __restrict__ out) {
  int idx = (blockIdx.x * 256 + threadIdx.x) * 4;   // 2*128*4096 total
  f32x4 s = {0.f, 0.f, 0.f, 0.f};
#pragma unroll
  for (int ks = 0; ks < 4; ++ks) {
    f32x4 v = *(const f32x4*)(part + (size_t)ks * (2 * CC * L) + idx);
#pragma unroll
    for (int e = 0; e < 4; ++e) s[e] += v[e];
  }
  int p = idx & (L - 1);
  int u = p >> 6, vv = p & 63;
  f32x4 o;
#pragma unroll
  for (int e = 0; e < 4; ++e) o[e] = (u < 63 && (vv + e) < 63) ? s[e] * 0.25f : 0.f;
  *(f32x4*)(out + idx) = o;
}

extern "C" void kernel_launch(void* const* d_in, const int* in_sizes, int n_in,
                              void* d_out, int out_size, void* d_ws, size_t ws_size,
                              hipStream_t stream) {
  const float* f = (const float*)d_in[0];
  const float* b = (const float*)d_in[1];
  const float* mask = (const float*)d_in[2];
  float* out = (float*)d_out;
  char* ws = (char*)d_ws;

  float* T3  = (float*)(ws + 0);           // 134,217,728
  f16* S     = (f16*)(ws + 134217728);     // 67,108,864
  f16* bm    = (f16*)(ws + 201326592);     // 8,388,608
  float* part= (float*)(ws + 209715200);   // 16,777,216
  float* pm  = (float*)(ws + 226492416);   // 8,388,608
  float* pl  = (float*)(ws + 234881024);   // 8,388,608
  float* mmv = (float*)(ws + 243269632);   // 16,384
  float* Mq  = (float*)(ws + 243286016);   // 32,768
  float* iLq = (float*)(ws + 243318784);   // 32,768
  f16* bT    = (f16*)(ws + 243351552);     // 2,097,152
  f16* fT    = (f16*)(ws + 245448704);     // 2,097,152
  float* ssq = (float*)(ws + 247545856);   // 32,768
  float* invn= (float*)(ws + 247578624);   // 32,768
  f16* zp    = (f16*)(ws + 247611392);     // 64

  k_repack<<<dim3(64, 4), dim3(256), 0, stream>>>(b, f, bT, fT, zp);
  k_ssq<<<dim3(16, 2), dim3(256), 0, stream>>>(b, ssq);
  k_norm<<<dim3(32), dim3(256), 0, stream>>>(ssq, invn);
  k_prep_bm<<<dim3(2048), dim3(256), 0, stream>>>(b, bm);
  k_prep_mm<<<dim3(16), dim3(256), 0, stream>>>(mask, mmv);
  k_gemm_scores<<<dim3(32, 32, 2), dim3(256), 0, stream>>>(bT, fT, invn, zp, S);
  k_fuse_stats<<<dim3(2, 256, 2), dim3(256), 0, stream>>>(S, mmv, T3, pm, pl);
  k_fuse_stats_edge<<<dim3(256, 2), dim3(256), 0, stream>>>(S, mmv, T3, pm, pl);
  k_softmax_reduce<<<dim3(32), dim3(256), 0, stream>>>(pm, pl, Mq, iLq);
  k_agg<<<dim3(64, 4, 2), dim3(512), 0, stream>>>(T3, mmv, Mq, iLq, bm, part);
  k_agg_reduce<<<dim3(1024), dim3(256), 0, stream>>>(part, out);
}

// Round 9
// 374.425 us; speedup vs baseline: 1.4093x; 1.0073x over previous
//
#include <hip/hip_runtime.h>

#define L 4096
#define HH 64
#define CC 128
#define BB 2

typedef _Float16 f16;
typedef _Float16 f16x8 __attribute__((ext_vector_type(8)));
typedef float f32x4 __attribute__((ext_vector_type(4)));

__device__ __forceinline__ void gl_lds16(const f16* g, f16* l) {
  __builtin_amdgcn_global_load_lds(
      (const __attribute__((address_space(1))) void*)g,
      (__attribute__((address_space(3))) void*)l, 16, 0, 0);
}

// sigma: involution converting row-major flat <-> col-major flat (64x64)
__device__ __forceinline__ int sigma_(int j) { return ((j & 63) << 6) | (j >> 6); }

// full 9-tap fused score from S (reference wrap semantics), scalar (edge columns)
__device__ float fuse9(const f16* __restrict__ Sb, int k, int j) {
  float acc = 0.f;
  int cK = sigma_(k), cQ = sigma_(j);
#pragma unroll
  for (int u = -1; u <= 1; ++u) {
    int a = cK + u, bq = cQ + u;
    if ((unsigned)a < L && (unsigned)bq < L) {
      int r = sigma_(a), c = sigma_(bq);
#pragma unroll
      for (int t = -1; t <= 1; ++t) {
        int rr = r + t, cc = c + t;
        if ((unsigned)rr < L && (unsigned)cc < L) acc += (float)Sb[(size_t)rr * L + cc];
      }
    }
  }
  return acc;
}

// ---------------- kernel 0a: repack [c][u] f32 -> [u][c] f16 (b and f), zero zeropage ----
__global__ __launch_bounds__(256) void k_repack(
    const float* __restrict__ b, const float* __restrict__ f,
    f16* __restrict__ bT, f16* __restrict__ fT, f16* __restrict__ zp) {
  __shared__ float tile[128][65];
  int u0 = blockIdx.x * 64;
  int z = blockIdx.y;            // batch*2 + tensor
  int batch = z >> 1;
  const float* src = ((z & 1) ? f : b) + (size_t)batch * CC * L;
  f16* dst = ((z & 1) ? fT : bT) + (size_t)batch * L * CC;
  int tid = threadIdx.x;
  if (blockIdx.x == 0 && z == 0 && tid < 32) zp[tid] = (f16)0.f;
#pragma unroll
  for (int i = 0; i < 32; ++i) {
    int idx = i * 256 + tid;
    int c = idx >> 6, ux = idx & 63;
    tile[c][ux] = src[(size_t)c * L + u0 + ux];
  }
  __syncthreads();
#pragma unroll
  for (int j = 0; j < 4; ++j) {
    int t2 = j * 256 + tid;
    int u = t2 >> 4, ch = t2 & 15;
    f16x8 v;
#pragma unroll
    for (int e = 0; e < 8; ++e) v[e] = (f16)tile[ch * 8 + e][u];
    *(f16x8*)(dst + (size_t)(u0 + u) * CC + ch * 8) = v;
  }
}

// ---------------- kernel 0b: ssq[batch][u] = sum_c b[c][u]^2 -----------------------------
__global__ __launch_bounds__(256) void k_ssq(const float* __restrict__ b, float* __restrict__ ssq) {
  int u = blockIdx.x * 256 + threadIdx.x;
  int batch = blockIdx.y;
  const float* bp = b + (size_t)batch * CC * L + u;
  float s = 0.f;
#pragma unroll 4
  for (int c = 0; c < CC; ++c) { float v = bp[(size_t)c * L]; s += v * v; }
  ssq[batch * L + u] = s;
}

// ---------------- kernel 0c: inv_n[batch][k] = 1/max(sqrt(sum_{r valid} ssq),1e-4) -------
__global__ void k_norm(const float* __restrict__ ssq, float* __restrict__ inv_n) {
  int gi = blockIdx.x * 256 + threadIdx.x;
  if (gi >= BB * L) return;
  int batch = gi >> 12, k = gi & (L - 1);
  int ky = k >> 6, kx = k & 63;
  float s = 0.f;
#pragma unroll
  for (int dy = -1; dy <= 1; ++dy)
#pragma unroll
    for (int dx = -1; dx <= 1; ++dx) {
      if ((unsigned)(ky + dy) < 64 && (unsigned)(kx + dx) < 64)
        s += ssq[batch * L + k + dy * 64 + dx];
    }
  inv_n[gi] = 1.f / fmaxf(sqrtf(s), 1e-4f);
}

// ---------------- kernel 1b: shifted+masked f16 copies of b (vectorized) -----------------
__global__ __launch_bounds__(256) void k_prep_bm(const float* __restrict__ b, f16* __restrict__ bm) {
  int idx = blockIdx.x * 256 + threadIdx.x;  // x8 elements
  int e8 = idx * 8;
  int k0 = e8 & (L - 1);
  int c = (e8 >> 12) & (CC - 1);
  int bt = e8 >> 19;            // tap*2 + batch
  int batch = bt & 1;
  int tap = bt >> 1;
  int di = 1 - (tap >> 1), dj = 1 - (tap & 1);
  int ky = k0 >> 6, kx0 = k0 & 63;
  const float* src = b + ((size_t)batch * CC + c) * L + k0 + di * 64 + dj;
  bool rowok = (ky + di) < 64;
  f16x8 v;
#pragma unroll
  for (int e = 0; e < 8; ++e) {
    float x = (rowok && (kx0 + e + dj) < 64) ? src[e] : 0.f;
    v[e] = (f16)x;
  }
  *(f16x8*)(bm + (size_t)e8) = v;
}

// ---------------- kernel 1c: mask validity mm[k] -----------------------------------------
__global__ void k_prep_mm(const float* __restrict__ mask, float* __restrict__ mmv) {
  int k = blockIdx.x * 256 + threadIdx.x;
  if (k >= L) return;
  int ky = k >> 6, kx = k & 63;
  float s = 0.f;
  for (int i = 0; i < 3; ++i)
    for (int j = 0; j < 3; ++j) {
      int yy = ky + i - 1, xx = kx + j - 1;
      if (yy >= 0 && yy < 64 && xx >= 0 && xx < 64) s += mask[yy * 64 + xx];
    }
  mmv[k] = (s == 0.f) ? 1.f : 0.f;
}

// ---------------- kernel 2: implicit-patch scores GEMM, hoisted addressing ---------------
// S[k,q] = inv_n[k] * sum_{r in 3x3} [valid] <b[:,k+r], f[:,q+r]>
// 128x128 tile, 4 waves (2x2), f16 MFMA 16x16x32; 18 stage-steps = 9 shifts x 2 c-halves;
// each staged 64-channel half is consumed by TWO compute passes (h2=0,1) of 16 MFMAs.
__global__ __launch_bounds__(256) void k_gemm_scores(
    const f16* __restrict__ bT, const f16* __restrict__ fT,
    const float* __restrict__ inv_n, const f16* __restrict__ zp,
    f16* __restrict__ S) {
  __shared__ f16 As[128 * 64];
  __shared__ f16 Bs[128 * 64];
  int qt = blockIdx.x, kt = blockIdx.y, batch = blockIdx.z;
  int tid = threadIdx.x, wid = tid >> 6, lane = tid & 63;
  int wr = wid >> 1, wc = wid & 1;
  const f16* A0 = bT + (size_t)batch * L * CC;
  const f16* B0 = fT + (size_t)batch * L * CC;
  f32x4 acc[4][4] = {};
  int rA = wr * 64 + (lane & 15);
  int rB = wc * 64 + (lane & 15);

  // ---- hoisted staging state ----
  const f16* baseA_[4]; const f16* baseB_[4];
  f16* ldsA_[4]; f16* ldsB_[4];
  unsigned mA_[4], mB_[4];
#pragma unroll
  for (int i = 0; i < 4; ++i) {
    int chunk = (i * 4 + wid) * 64 + lane;         // 0..1023
    int row = chunk >> 3;                          // 0..127
    int lg = (lane & 7) ^ (row & 7);               // pre-swizzled source chunk
    int k = kt * 128 + row;
    int q = qt * 128 + row;
    baseA_[i] = A0 + (size_t)k * CC + lg * 8;
    baseB_[i] = B0 + (size_t)q * CC + lg * 8;
    ldsA_[i] = As + chunk * 8;
    ldsB_[i] = Bs + chunk * 8;
    int ky = k >> 6, kx = k & 63, qy = q >> 6, qx = q & 63;
    unsigned ma = 0, mb = 0;
#pragma unroll
    for (int rr = 0; rr < 9; ++rr) {
      int dy = rr / 3 - 1, dx = rr - (rr / 3) * 3 - 1;
      if ((unsigned)(ky + dy) < 64u && (unsigned)(kx + dx) < 64u) ma |= 1u << rr;
      if ((unsigned)(qy + dy) < 64u && (unsigned)(qx + dx) < 64u) mb |= 1u << rr;
    }
    mA_[i] = ma; mB_[i] = mb;
  }

#pragma unroll 1
  for (int t = 0; t < 18; ++t) {
    int rr = t >> 1, half = t & 1;
    int dy = rr / 3 - 1, dx = rr - (rr / 3) * 3 - 1;
    int doff = (dy * 64 + dx) * CC + half * 64;    // wave-uniform
    __syncthreads();
#pragma unroll
    for (int i = 0; i < 4; ++i) {
      gl_lds16(((mA_[i] >> rr) & 1u) ? (baseA_[i] + doff) : zp, ldsA_[i]);
      gl_lds16(((mB_[i] >> rr) & 1u) ? (baseB_[i] + doff) : zp, ldsB_[i]);
    }
    __syncthreads();
#pragma unroll
    for (int h2 = 0; h2 < 2; ++h2) {
      int cb = h2 * 4 + (lane >> 4);               // logical chunk within LDS row
      f16x8 af[4], bf[4];
#pragma unroll
      for (int m = 0; m < 4; ++m) {
        int row = rA + m * 16;
        af[m] = *(const f16x8*)(As + row * 64 + ((cb ^ (row & 7)) * 8));
      }
#pragma unroll
      for (int n = 0; n < 4; ++n) {
        int row = rB + n * 16;
        bf[n] = *(const f16x8*)(Bs + row * 64 + ((cb ^ (row & 7)) * 8));
      }
#pragma unroll
      for (int m = 0; m < 4; ++m)
#pragma unroll
        for (int n = 0; n < 4; ++n)
          acc[m][n] = __builtin_amdgcn_mfma_f32_16x16x32_f16(af[m], bf[n], acc[m][n], 0, 0, 0);
    }
  }
  f16* Srow = S + (size_t)batch * L * L;
  int kbase = kt * 128 + wr * 64 + (lane >> 4) * 4;
  int qbase = qt * 128 + wc * 64 + (lane & 15);
#pragma unroll
  for (int m = 0; m < 4; ++m) {
    f32x4 invv = *(const f32x4*)(inv_n + (size_t)batch * L + kbase + m * 16);
#pragma unroll
    for (int r = 0; r < 4; ++r) {
      f16* dst = Srow + (size_t)(kbase + m * 16 + r) * L + qbase;
#pragma unroll
      for (int n = 0; n < 4; ++n) dst[n * 16] = (f16)(acc[m][n][r] * invv[r]);
    }
  }
}

// ---------------- kernel 3: fused stencil -> T3 + online softmax partials ----------------
__global__ __launch_bounds__(256) void k_fuse_stats(
    const f16* __restrict__ S, const float* __restrict__ mmv,
    float* __restrict__ T3, float* __restrict__ pm, float* __restrict__ pl) {
  int tid = threadIdx.x;
  if (tid >= 247) return;
  int jc = blockIdx.x, kc = blockIdx.y, batch = blockIdx.z;
  int g = jc * 247 + tid;                  // 0..493
  int q0 = 72 + g * 8;                     // aligned, fully interior group
  const f16* Sb = S + (size_t)batch * L * L;
  float* Tb = T3 + (size_t)batch * L * L;
  float m8[8], l8[8];
#pragma unroll
  for (int e = 0; e < 8; ++e) { m8[e] = -3.0e38f; l8[e] = 0.f; }
  int cnt = 0;
  int k0 = kc * 16;
  for (int kk = 0; kk < 16; ++kk) {
    int k = k0 + kk;
    if (mmv[k] == 0.f) { ++cnt; continue; }
    float acc[8] = {0.f, 0.f, 0.f, 0.f, 0.f, 0.f, 0.f, 0.f};
    int cK = sigma_(k);
#pragma unroll
    for (int u = -1; u <= 1; ++u) {
      int a = cK + u;
      if ((unsigned)a >= L) continue;
      int r = sigma_(a);                   // = k + 64u for interior k
      const f16* cb = Sb + (size_t)r * L + (q0 + 64 * u);
      {
        f16x8 v = *(const f16x8*)cb;
#pragma unroll
        for (int e = 0; e < 8; ++e) acc[e] += (float)v[e];
      }
      if (r >= 1) {
        const f16* rm = cb - L;
        f16x8 v = *(const f16x8*)rm;
        acc[0] += (float)rm[-1];
#pragma unroll
        for (int e = 1; e < 8; ++e) acc[e] += (float)v[e - 1];
      }
      if (r <= L - 2) {
        const f16* rp = cb + L;
        f16x8 v = *(const f16x8*)rp;
#pragma unroll
        for (int e = 0; e < 7; ++e) acc[e] += (float)v[e + 1];
        acc[7] += (float)rp[8];
      }
    }
#pragma unroll
    for (int e = 0; e < 8; ++e) acc[e] *= 10.f;
    float* trow = Tb + (size_t)k * L + q0;
    *(f32x4*)trow = *(f32x4*)&acc[0];
    *(f32x4*)(trow + 4) = *(f32x4*)&acc[4];
#pragma unroll
    for (int e = 0; e < 8; ++e) {
      float nm = fmaxf(m8[e], acc[e]);
      l8[e] = l8[e] * __expf(m8[e] - nm) + __expf(acc[e] - nm);
      m8[e] = nm;
    }
  }
  float fc = (float)cnt;
  float om[8], ol[8];
#pragma unroll
  for (int e = 0; e < 8; ++e) {
    float nm = fmaxf(m8[e], 0.f);
    ol[e] = l8[e] * __expf(m8[e] - nm) + fc * __expf(-nm);
    om[e] = nm;
  }
  float* pmp = pm + (size_t)kc * (BB * L) + (size_t)batch * L + q0;
  float* plp = pl + (size_t)kc * (BB * L) + (size_t)batch * L + q0;
  *(f32x4*)pmp = *(f32x4*)&om[0]; *(f32x4*)(pmp + 4) = *(f32x4*)&om[4];
  *(f32x4*)plp = *(f32x4*)&ol[0]; *(f32x4*)(plp + 4) = *(f32x4*)&ol[4];
}

// ---------------- kernel 3e: edge q columns (144 cols), scalar fuse9 ---------------------
__global__ __launch_bounds__(256) void k_fuse_stats_edge(
    const f16* __restrict__ S, const float* __restrict__ mmv,
    float* __restrict__ T3, float* __restrict__ pm, float* __restrict__ pl) {
  int tid = threadIdx.x;
  if (tid >= 144) return;
  int q = (tid < 72) ? tid : (4024 + tid - 72);
  int kc = blockIdx.x, batch = blockIdx.y;
  const f16* Sb = S + (size_t)batch * L * L;
  float* Tb = T3 + (size_t)batch * L * L;
  float m = -3.0e38f, l = 0.f;
  int cnt = 0;
  int k0 = kc * 16;
  for (int kk = 0; kk < 16; ++kk) {
    int k = k0 + kk;
    if (mmv[k] == 0.f) { ++cnt; continue; }
    float logit = 10.f * fuse9(Sb, k, q);
    Tb[(size_t)k * L + q] = logit;
    float nm = fmaxf(m, logit);
    l = l * __expf(m - nm) + __expf(logit - nm);
    m = nm;
  }
  float nm = fmaxf(m, 0.f);
  l = l * __expf(m - nm) + (float)cnt * __expf(-nm);
  pm[(size_t)kc * (BB * L) + (size_t)batch * L + q] = nm;
  pl[(size_t)kc * (BB * L) + (size_t)batch * L + q] = l;
}

// ---------------- kernel 3b: combine partials; store M and 1/L ---------------------------
__global__ void k_softmax_reduce(const float* __restrict__ pm, const float* __restrict__ pl,
                                 float* __restrict__ Mq, float* __restrict__ invLq) {
  int qi = blockIdx.x * 256 + threadIdx.x;
  if (qi >= BB * L) return;
  float M = -3.0e38f;
  for (int i = 0; i < 256; ++i) M = fmaxf(M, pm[(size_t)i * (BB * L) + qi]);
  float Ls = 0.f;
  for (int i = 0; i < 256; ++i) Ls += pl[(size_t)i * (BB * L) + qi] * __expf(pm[(size_t)i * (BB * L) + qi] - M);
  Mq[qi] = M;
  invLq[qi] = 1.f / Ls;
}

// ---------------- kernel 5: aggregation with fused softmax-exp B-staging -----------------
__global__ __launch_bounds__(512) void k_agg(
    const float* __restrict__ T3, const float* __restrict__ mmv,
    const float* __restrict__ Mq, const float* __restrict__ invLq,
    const f16* __restrict__ bm, float* __restrict__ part) {
  __shared__ f16 Asm[512 * 32];   // [R=tap*128+c][32kk], chunk-swizzled: phys = log ^ ((R>>1)&3)
  __shared__ f16 Bt[136 * 40];    // [pp][kk], kk-chunk swizzled: phys = log ^ ((pp>>3)&3)
  int pt = blockIdx.x, ks = blockIdx.y, batch = blockIdx.z;
  int p0 = pt * 64;
  int tid = threadIdx.x, wid = tid >> 6, lane = tid & 63;
  int wr = wid >> 1, wc = wid & 1;
  const float* Tb = T3 + (size_t)batch * L * L;
  const float* mq0 = Mq + (size_t)batch * L;
  const float* il0 = invLq + (size_t)batch * L;
  f32x4 acc[2][2] = {};
  int kend = ks * 1024 + 1024;
  for (int k0 = ks * 1024; k0 < kend; k0 += 32) {
    __syncthreads();
#pragma unroll
    for (int i = 0; i < 4; ++i) {
      int R = wid * 64 + i * 16 + (lane >> 2);
      int tap = R >> 7, c = R & 127;
      int chl = (lane & 3) ^ ((R >> 1) & 3);
      const f16* g = bm + (((size_t)(tap * 2 + batch) * CC + c) * L) + k0 + chl * 8;
      gl_lds16(g, Asm + R * 32 + (lane & 3) * 8);
    }
    // B staging: Bt[pp][kk] = attn(k0+kk, p0+pp) with exp fused, 544 tasks
    for (int tau = tid; tau < 544; tau += 512) {
      int kk = tau / 17, ch = tau - kk * 17;
      int k = k0 + kk;
      int pbase = p0 + ch * 8;
      f16 v[8];
      if (mmv[k] != 0.f) {
        const float* trow = Tb + (size_t)k * L + pbase;
        if (pbase + 7 < L) {
          f32x4 t0 = *(const f32x4*)trow;
          f32x4 t1 = *(const f32x4*)(trow + 4);
          f32x4 m0 = *(const f32x4*)(mq0 + pbase);
          f32x4 m1 = *(const f32x4*)(mq0 + pbase + 4);
          f32x4 i0 = *(const f32x4*)(il0 + pbase);
          f32x4 i1 = *(const f32x4*)(il0 + pbase + 4);
#pragma unroll
          for (int e = 0; e < 4; ++e) v[e] = (f16)(__expf(t0[e] - m0[e]) * i0[e]);
#pragma unroll
          for (int e = 0; e < 4; ++e) v[4 + e] = (f16)(__expf(t1[e] - m1[e]) * i1[e]);
        } else {
#pragma unroll
          for (int e = 0; e < 8; ++e) {
            int q = pbase + e;
            v[e] = (q < L) ? (f16)(__expf(trow[e] - mq0[q]) * il0[q]) : (f16)0.f;
          }
        }
      } else {
#pragma unroll
        for (int e = 0; e < 8; ++e) v[e] = (f16)0.f;
      }
#pragma unroll
      for (int e = 0; e < 8; ++e) {
        int pp = ch * 8 + e;
        Bt[pp * 40 + (((kk >> 3) ^ ((pp >> 3) & 3)) * 8) + (kk & 7)] = v[e];
      }
    }
    __syncthreads();
#pragma unroll
    for (int tap = 0; tap < 4; ++tap) {
      int dlt = (tap >> 1) * 64 + (tap & 1);
      f16x8 af[2], bf[2];
#pragma unroll
      for (int m = 0; m < 2; ++m) {
        int R = tap * 128 + wr * 32 + m * 16 + (lane & 15);
        int ph = (lane >> 4) ^ ((R >> 1) & 3);
        af[m] = *(const f16x8*)(Asm + R * 32 + ph * 8);
      }
#pragma unroll
      for (int n = 0; n < 2; ++n) {
        int pp = wc * 32 + n * 16 + (lane & 15) + dlt;
        int ph = (lane >> 4) ^ ((pp >> 3) & 3);
        bf[n] = *(const f16x8*)(Bt + pp * 40 + ph * 8);
      }
#pragma unroll
      for (int m = 0; m < 2; ++m)
#pragma unroll
        for (int n = 0; n < 2; ++n)
          acc[m][n] = __builtin_amdgcn_mfma_f32_16x16x32_f16(af[m], bf[n], acc[m][n], 0, 0, 0);
    }
  }
  int cb = wr * 32 + (lane >> 4) * 4;
  int pb = p0 + wc * 32 + (lane & 15);
#pragma unroll
  for (int m = 0; m < 2; ++m)
#pragma unroll
    for (int n = 0; n < 2; ++n)
#pragma unroll
      for (int r = 0; r < 4; ++r) {
        int c = cb + m * 16 + r;
        int p = pb + n * 16;
        part[(((size_t)ks * 2 + batch) * CC + c) * L + p] = acc[m][n][r];
      }
}

// ---------------- kernel 5b: sum K-split partials, scale, border mask (vectorized) -------
__global__ __launch_bounds__(256) void k_agg_reduce(const float* __restrict__ part, float* __restrict__ out) {
  int idx = (blockIdx.x * 256 + threadIdx.x) * 4;   // 2*128*4096 total
  f32x4 s = {0.f, 0.f, 0.f, 0.f};
#pragma unroll
  for (int ks = 0; ks < 4; ++ks) {
    f32x4 v = *(const f32x4*)(part + (size_t)ks * (2 * CC * L) + idx);
#pragma unroll
    for (int e = 0; e < 4; ++e) s[e] += v[e];
  }
  int p = idx & (L - 1);
  int u = p >> 6, vv = p & 63;
  f32x4 o;
#pragma unroll
  for (int e = 0; e < 4; ++e) o[e] = (u < 63 && (vv + e) < 63) ? s[e] * 0.25f : 0.f;
  *(f32x4*)(out + idx) = o;
}

extern "C" void kernel_launch(void* const* d_in, const int* in_sizes, int n_in,
                              void* d_out, int out_size, void* d_ws, size_t ws_size,
                              hipStream_t stream) {
  const float* f = (const float*)d_in[0];
  const float* b = (const float*)d_in[1];
  const float* mask = (const float*)d_in[2];
  float* out = (float*)d_out;
  char* ws = (char*)d_ws;

  float* T3  = (float*)(ws + 0);           // 134,217,728
  f16* S     = (f16*)(ws + 134217728);     // 67,108,864
  f16* bm    = (f16*)(ws + 201326592);     // 8,388,608
  float* part= (float*)(ws + 209715200);   // 16,777,216
  float* pm  = (float*)(ws + 226492416);   // 8,388,608
  float* pl  = (float*)(ws + 234881024);   // 8,388,608
  float* mmv = (float*)(ws + 243269632);   // 16,384
  float* Mq  = (float*)(ws + 243286016);   // 32,768
  float* iLq = (float*)(ws + 243318784);   // 32,768
  f16* bT    = (f16*)(ws + 243351552);     // 2,097,152
  f16* fT    = (f16*)(ws + 245448704);     // 2,097,152
  float* ssq = (float*)(ws + 247545856);   // 32,768
  float* invn= (float*)(ws + 247578624);   // 32,768
  f16* zp    = (f16*)(ws + 247611392);     // 64

  k_repack<<<dim3(64, 4), dim3(256), 0, stream>>>(b, f, bT, fT, zp);
  k_ssq<<<dim3(16, 2), dim3(256), 0, stream>>>(b, ssq);
  k_norm<<<dim3(32), dim3(256), 0, stream>>>(ssq, invn);
  k_prep_bm<<<dim3(2048), dim3(256), 0, stream>>>(b, bm);
  k_prep_mm<<<dim3(16), dim3(256), 0, stream>>>(mask, mmv);
  k_gemm_scores<<<dim3(32, 32, 2), dim3(256), 0, stream>>>(bT, fT, invn, zp, S);
  k_fuse_stats<<<dim3(2, 256, 2), dim3(256), 0, stream>>>(S, mmv, T3, pm, pl);
  k_fuse_stats_edge<<<dim3(256, 2), dim3(256), 0, stream>>>(S, mmv, T3, pm, pl);
  k_softmax_reduce<<<dim3(32), dim3(256), 0, stream>>>(pm, pl, Mq, iLq);
  k_agg<<<dim3(64, 4, 2), dim3(512), 0, stream>>>(T3, mmv, Mq, iLq, bm, part);
  k_agg_reduce<<<dim3(1024), dim3(256), 0, stream>>>(part, out);
}

// Round 10
// 320.962 us; speedup vs baseline: 1.6441x; 1.1666x over previous
//
#include <hip/hip_runtime.h>

#define L 4096
#define HH 64
#define CC 128
#define BB 2

typedef _Float16 f16;
typedef _Float16 f16x8 __attribute__((ext_vector_type(8)));
typedef float f32x4 __attribute__((ext_vector_type(4)));

__device__ __forceinline__ void gl_lds16(const f16* g, f16* l) {
  __builtin_amdgcn_global_load_lds(
      (const __attribute__((address_space(1))) void*)g,
      (__attribute__((address_space(3))) void*)l, 16, 0, 0);
}

// sigma: involution converting row-major flat <-> col-major flat (64x64)
__device__ __forceinline__ int sigma_(int j) { return ((j & 63) << 6) | (j >> 6); }

// full 9-tap fused score from S (reference wrap semantics), scalar (edge columns)
__device__ float fuse9(const f16* __restrict__ Sb, int k, int j) {
  float acc = 0.f;
  int cK = sigma_(k), cQ = sigma_(j);
#pragma unroll
  for (int u = -1; u <= 1; ++u) {
    int a = cK + u, bq = cQ + u;
    if ((unsigned)a < L && (unsigned)bq < L) {
      int r = sigma_(a), c = sigma_(bq);
#pragma unroll
      for (int t = -1; t <= 1; ++t) {
        int rr = r + t, cc = c + t;
        if ((unsigned)rr < L && (unsigned)cc < L) acc += (float)Sb[(size_t)rr * L + cc];
      }
    }
  }
  return acc;
}

// ---------------- kernel 0a: repack [c][u] f32 -> [u][c] f16 (b and f), zero zeropage ----
__global__ __launch_bounds__(256) void k_repack(
    const float* __restrict__ b, const float* __restrict__ f,
    f16* __restrict__ bT, f16* __restrict__ fT, f16* __restrict__ zp) {
  __shared__ float tile[128][65];
  int u0 = blockIdx.x * 64;
  int z = blockIdx.y;            // batch*2 + tensor
  int batch = z >> 1;
  const float* src = ((z & 1) ? f : b) + (size_t)batch * CC * L;
  f16* dst = ((z & 1) ? fT : bT) + (size_t)batch * L * CC;
  int tid = threadIdx.x;
  if (blockIdx.x == 0 && z == 0 && tid < 32) zp[tid] = (f16)0.f;
#pragma unroll
  for (int i = 0; i < 32; ++i) {
    int idx = i * 256 + tid;
    int c = idx >> 6, ux = idx & 63;
    tile[c][ux] = src[(size_t)c * L + u0 + ux];
  }
  __syncthreads();
#pragma unroll
  for (int j = 0; j < 4; ++j) {
    int t2 = j * 256 + tid;
    int u = t2 >> 4, ch = t2 & 15;
    f16x8 v;
#pragma unroll
    for (int e = 0; e < 8; ++e) v[e] = (f16)tile[ch * 8 + e][u];
    *(f16x8*)(dst + (size_t)(u0 + u) * CC + ch * 8) = v;
  }
}

// ---------------- kernel 0b: ssq[batch][u] = sum_c b[c][u]^2 -----------------------------
__global__ __launch_bounds__(256) void k_ssq(const float* __restrict__ b, float* __restrict__ ssq) {
  int u = blockIdx.x * 256 + threadIdx.x;
  int batch = blockIdx.y;
  const float* bp = b + (size_t)batch * CC * L + u;
  float s = 0.f;
#pragma unroll 4
  for (int c = 0; c < CC; ++c) { float v = bp[(size_t)c * L]; s += v * v; }
  ssq[batch * L + u] = s;
}

// ---------------- kernel 0c: inv_n[batch][k] = 1/max(sqrt(sum_{r valid} ssq),1e-4) -------
__global__ void k_norm(const float* __restrict__ ssq, float* __restrict__ inv_n) {
  int gi = blockIdx.x * 256 + threadIdx.x;
  if (gi >= BB * L) return;
  int batch = gi >> 12, k = gi & (L - 1);
  int ky = k >> 6, kx = k & 63;
  float s = 0.f;
#pragma unroll
  for (int dy = -1; dy <= 1; ++dy)
#pragma unroll
    for (int dx = -1; dx <= 1; ++dx) {
      if ((unsigned)(ky + dy) < 64 && (unsigned)(kx + dx) < 64)
        s += ssq[batch * L + k + dy * 64 + dx];
    }
  inv_n[gi] = 1.f / fmaxf(sqrtf(s), 1e-4f);
}

// ---------------- kernel 1b: shifted+masked f16 copies of b (vectorized) -----------------
__global__ __launch_bounds__(256) void k_prep_bm(const float* __restrict__ b, f16* __restrict__ bm) {
  int idx = blockIdx.x * 256 + threadIdx.x;  // x8 elements
  int e8 = idx * 8;
  int k0 = e8 & (L - 1);
  int c = (e8 >> 12) & (CC - 1);
  int bt = e8 >> 19;            // tap*2 + batch
  int batch = bt & 1;
  int tap = bt >> 1;
  int di = 1 - (tap >> 1), dj = 1 - (tap & 1);
  int ky = k0 >> 6, kx0 = k0 & 63;
  const float* src = b + ((size_t)batch * CC + c) * L + k0 + di * 64 + dj;
  bool rowok = (ky + di) < 64;
  f16x8 v;
#pragma unroll
  for (int e = 0; e < 8; ++e) {
    float x = (rowok && (kx0 + e + dj) < 64) ? src[e] : 0.f;
    v[e] = (f16)x;
  }
  *(f16x8*)(bm + (size_t)e8) = v;
}

// ---------------- kernel 1c: mask validity mm[k] -----------------------------------------
__global__ void k_prep_mm(const float* __restrict__ mask, float* __restrict__ mmv) {
  int k = blockIdx.x * 256 + threadIdx.x;
  if (k >= L) return;
  int ky = k >> 6, kx = k & 63;
  float s = 0.f;
  for (int i = 0; i < 3; ++i)
    for (int j = 0; j < 3; ++j) {
      int yy = ky + i - 1, xx = kx + j - 1;
      if (yy >= 0 && yy < 64 && xx >= 0 && xx < 64) s += mask[yy * 64 + xx];
    }
  mmv[k] = (s == 0.f) ? 1.f : 0.f;
}

// ---------------- kernel 2: implicit-patch scores GEMM, 2-phase double-buffered ----------
// S[k,q] = inv_n[k] * sum_{r in 3x3} [valid] <b[:,k+r], f[:,q+r]>
// 128x128 tile, 4 waves (2x2), f16 MFMA 16x16x32; 18 stage-steps = 9 shifts x 2 c-halves;
// Double-buffered LDS: STAGE(t+1, buf^1) issued BEFORE compute(buf); one barrier/step
// (compiler's vmcnt(0)+lgkmcnt(0) drain at __syncthreads covers the async loads).
__global__ __launch_bounds__(256) void k_gemm_scores(
    const f16* __restrict__ bT, const f16* __restrict__ fT,
    const float* __restrict__ inv_n, const f16* __restrict__ zp,
    f16* __restrict__ S) {
  __shared__ f16 As[2][128 * 64];
  __shared__ f16 Bs[2][128 * 64];
  int qt = blockIdx.x, kt = blockIdx.y, batch = blockIdx.z;
  int tid = threadIdx.x, wid = tid >> 6, lane = tid & 63;
  int wr = wid >> 1, wc = wid & 1;
  const f16* A0 = bT + (size_t)batch * L * CC;
  const f16* B0 = fT + (size_t)batch * L * CC;
  f32x4 acc[4][4] = {};
  int rA = wr * 64 + (lane & 15);
  int rB = wc * 64 + (lane & 15);

  // ---- hoisted staging state ----
  const f16* baseA_[4]; const f16* baseB_[4];
  int offL_[4];
  unsigned mA_[4], mB_[4];
#pragma unroll
  for (int i = 0; i < 4; ++i) {
    int chunk = (i * 4 + wid) * 64 + lane;         // 0..1023
    int row = chunk >> 3;                          // 0..127
    int lg = (lane & 7) ^ (row & 7);               // pre-swizzled source chunk
    int k = kt * 128 + row;
    int q = qt * 128 + row;
    baseA_[i] = A0 + (size_t)k * CC + lg * 8;
    baseB_[i] = B0 + (size_t)q * CC + lg * 8;
    offL_[i] = chunk * 8;
    int ky = k >> 6, kx = k & 63, qy = q >> 6, qx = q & 63;
    unsigned ma = 0, mb = 0;
#pragma unroll
    for (int rr = 0; rr < 9; ++rr) {
      int dy = rr / 3 - 1, dx = rr - (rr / 3) * 3 - 1;
      if ((unsigned)(ky + dy) < 64u && (unsigned)(kx + dx) < 64u) ma |= 1u << rr;
      if ((unsigned)(qy + dy) < 64u && (unsigned)(qx + dx) < 64u) mb |= 1u << rr;
    }
    mA_[i] = ma; mB_[i] = mb;
  }

#define STAGE_T(tt, bsel)                                                     \
  do {                                                                        \
    int rr_ = (tt) >> 1, half_ = (tt) & 1;                                    \
    int dy_ = rr_ / 3 - 1, dx_ = rr_ - (rr_ / 3) * 3 - 1;                     \
    int doff_ = (dy_ * 64 + dx_) * CC + half_ * 64;                           \
    _Pragma("unroll")                                                         \
    for (int i = 0; i < 4; ++i) {                                             \
      gl_lds16(((mA_[i] >> rr_) & 1u) ? (baseA_[i] + doff_) : zp,             \
               &As[bsel][0] + offL_[i]);                                      \
      gl_lds16(((mB_[i] >> rr_) & 1u) ? (baseB_[i] + doff_) : zp,             \
               &Bs[bsel][0] + offL_[i]);                                      \
    }                                                                         \
  } while (0)

  STAGE_T(0, 0);
  int cur = 0;
#pragma unroll 1
  for (int t = 0; t < 18; ++t) {
    __syncthreads();                       // drains stage of buf[cur]
    if (t < 17) STAGE_T(t + 1, cur ^ 1);   // in flight across this step's MFMAs
    const f16* Ab = &As[cur][0];
    const f16* Bb = &Bs[cur][0];
#pragma unroll
    for (int h2 = 0; h2 < 2; ++h2) {
      int cb = h2 * 4 + (lane >> 4);       // logical chunk within LDS row
      f16x8 af[4], bf[4];
#pragma unroll
      for (int m = 0; m < 4; ++m) {
        int row = rA + m * 16;
        af[m] = *(const f16x8*)(Ab + row * 64 + ((cb ^ (row & 7)) * 8));
      }
#pragma unroll
      for (int n = 0; n < 4; ++n) {
        int row = rB + n * 16;
        bf[n] = *(const f16x8*)(Bb + row * 64 + ((cb ^ (row & 7)) * 8));
      }
#pragma unroll
      for (int m = 0; m < 4; ++m)
#pragma unroll
        for (int n = 0; n < 4; ++n)
          acc[m][n] = __builtin_amdgcn_mfma_f32_16x16x32_f16(af[m], bf[n], acc[m][n], 0, 0, 0);
    }
    cur ^= 1;
  }
#undef STAGE_T

  f16* Srow = S + (size_t)batch * L * L;
  int kbase = kt * 128 + wr * 64 + (lane >> 4) * 4;
  int qbase = qt * 128 + wc * 64 + (lane & 15);
#pragma unroll
  for (int m = 0; m < 4; ++m) {
    f32x4 invv = *(const f32x4*)(inv_n + (size_t)batch * L + kbase + m * 16);
#pragma unroll
    for (int r = 0; r < 4; ++r) {
      f16* dst = Srow + (size_t)(kbase + m * 16 + r) * L + qbase;
#pragma unroll
      for (int n = 0; n < 4; ++n) dst[n * 16] = (f16)(acc[m][n][r] * invv[r]);
    }
  }
}

// ---------------- kernel 3: fused stencil -> T3 + online softmax partials ----------------
__global__ __launch_bounds__(256) void k_fuse_stats(
    const f16* __restrict__ S, const float* __restrict__ mmv,
    float* __restrict__ T3, float* __restrict__ pm, float* __restrict__ pl) {
  int tid = threadIdx.x;
  if (tid >= 247) return;
  int jc = blockIdx.x, kc = blockIdx.y, batch = blockIdx.z;
  int g = jc * 247 + tid;                  // 0..493
  int q0 = 72 + g * 8;                     // aligned, fully interior group
  const f16* Sb = S + (size_t)batch * L * L;
  float* Tb = T3 + (size_t)batch * L * L;
  float m8[8], l8[8];
#pragma unroll
  for (int e = 0; e < 8; ++e) { m8[e] = -3.0e38f; l8[e] = 0.f; }
  int cnt = 0;
  int k0 = kc * 16;
  for (int kk = 0; kk < 16; ++kk) {
    int k = k0 + kk;
    if (mmv[k] == 0.f) { ++cnt; continue; }
    float acc[8] = {0.f, 0.f, 0.f, 0.f, 0.f, 0.f, 0.f, 0.f};
    int cK = sigma_(k);
#pragma unroll
    for (int u = -1; u <= 1; ++u) {
      int a = cK + u;
      if ((unsigned)a >= L) continue;
      int r = sigma_(a);                   // = k + 64u for interior k
      const f16* cb = Sb + (size_t)r * L + (q0 + 64 * u);
      {
        f16x8 v = *(const f16x8*)cb;
#pragma unroll
        for (int e = 0; e < 8; ++e) acc[e] += (float)v[e];
      }
      if (r >= 1) {
        const f16* rm = cb - L;
        f16x8 v = *(const f16x8*)rm;
        acc[0] += (float)rm[-1];
#pragma unroll
        for (int e = 1; e < 8; ++e) acc[e] += (float)v[e - 1];
      }
      if (r <= L - 2) {
        const f16* rp = cb + L;
        f16x8 v = *(const f16x8*)rp;
#pragma unroll
        for (int e = 0; e < 7; ++e) acc[e] += (float)v[e + 1];
        acc[7] += (float)rp[8];
      }
    }
#pragma unroll
    for (int e = 0; e < 8; ++e) acc[e] *= 10.f;
    float* trow = Tb + (size_t)k * L + q0;
    *(f32x4*)trow = *(f32x4*)&acc[0];
    *(f32x4*)(trow + 4) = *(f32x4*)&acc[4];
#pragma unroll
    for (int e = 0; e < 8; ++e) {
      float nm = fmaxf(m8[e], acc[e]);
      l8[e] = l8[e] * __expf(m8[e] - nm) + __expf(acc[e] - nm);
      m8[e] = nm;
    }
  }
  float fc = (float)cnt;
  float om[8], ol[8];
#pragma unroll
  for (int e = 0; e < 8; ++e) {
    float nm = fmaxf(m8[e], 0.f);
    ol[e] = l8[e] * __expf(m8[e] - nm) + fc * __expf(-nm);
    om[e] = nm;
  }
  float* pmp = pm + (size_t)kc * (BB * L) + (size_t)batch * L + q0;
  float* plp = pl + (size_t)kc * (BB * L) + (size_t)batch * L + q0;
  *(f32x4*)pmp = *(f32x4*)&om[0]; *(f32x4*)(pmp + 4) = *(f32x4*)&om[4];
  *(f32x4*)plp = *(f32x4*)&ol[0]; *(f32x4*)(plp + 4) = *(f32x4*)&ol[4];
}

// ---------------- kernel 3e: edge q columns (144 cols), scalar fuse9 ---------------------
__global__ __launch_bounds__(256) void k_fuse_stats_edge(
    const f16* __restrict__ S, const float* __restrict__ mmv,
    float* __restrict__ T3, float* __restrict__ pm, float* __restrict__ pl) {
  int tid = threadIdx.x;
  if (tid >= 144) return;
  int q = (tid < 72) ? tid : (4024 + tid - 72);
  int kc = blockIdx.x, batch = blockIdx.y;
  const f16* Sb = S + (size_t)batch * L * L;
  float* Tb = T3 + (size_t)batch * L * L;
  float m = -3.0e38f, l = 0.f;
  int cnt = 0;
  int k0 = kc * 16;
  for (int kk = 0; kk < 16; ++kk) {
    int k = k0 + kk;
    if (mmv[k] == 0.f) { ++cnt; continue; }
    float logit = 10.f * fuse9(Sb, k, q);
    Tb[(size_t)k * L + q] = logit;
    float nm = fmaxf(m, logit);
    l = l * __expf(m - nm) + __expf(logit - nm);
    m = nm;
  }
  float nm = fmaxf(m, 0.f);
  l = l * __expf(m - nm) + (float)cnt * __expf(-nm);
  pm[(size_t)kc * (BB * L) + (size_t)batch * L + q] = nm;
  pl[(size_t)kc * (BB * L) + (size_t)batch * L + q] = l;
}

// ---------------- kernel 3b: combine partials; store M and 1/L (parallelized) ------------
// 128 blocks x 256 threads: 64 qi per block, 4 threads per qi each merging 64 chunks.
__global__ __launch_bounds__(256) void k_softmax_reduce(
    const float* __restrict__ pm, const float* __restrict__ pl,
    float* __restrict__ Mq, float* __restrict__ invLq) {
  __shared__ float sm[4][64], sl[4][64];
  int tid = threadIdx.x;
  int ql = tid & 63, part = tid >> 6;
  int qi = blockIdx.x * 64 + ql;
  float m = -3.0e38f, l = 0.f;
  int i0 = part * 64;
#pragma unroll 4
  for (int i = i0; i < i0 + 64; ++i) {
    float pmv = pm[(size_t)i * (BB * L) + qi];
    float plv = pl[(size_t)i * (BB * L) + qi];
    float nm = fmaxf(m, pmv);
    l = l * __expf(m - nm) + plv * __expf(pmv - nm);
    m = nm;
  }
  sm[part][ql] = m; sl[part][ql] = l;
  __syncthreads();
  if (part == 0) {
    float M = sm[0][ql];
#pragma unroll
    for (int p = 1; p < 4; ++p) M = fmaxf(M, sm[p][ql]);
    float Ls = 0.f;
#pragma unroll
    for (int p = 0; p < 4; ++p) Ls += sl[p][ql] * __expf(sm[p][ql] - M);
    Mq[qi] = M;
    invLq[qi] = 1.f / Ls;
  }
}

// ---------------- kernel 5: aggregation with fused softmax-exp B-staging -----------------
__global__ __launch_bounds__(512) void k_agg(
    const float* __restrict__ T3, const float* __restrict__ mmv,
    const float* __restrict__ Mq, const float* __restrict__ invLq,
    const f16* __restrict__ bm, float* __restrict__ part) {
  __shared__ f16 Asm[512 * 32];   // [R=tap*128+c][32kk], chunk-swizzled: phys = log ^ ((R>>1)&3)
  __shared__ f16 Bt[136 * 40];    // [pp][kk], kk-chunk swizzled: phys = log ^ ((pp>>3)&3)
  int pt = blockIdx.x, ks = blockIdx.y, batch = blockIdx.z;
  int p0 = pt * 64;
  int tid = threadIdx.x, wid = tid >> 6, lane = tid & 63;
  int wr = wid >> 1, wc = wid & 1;
  const float* Tb = T3 + (size_t)batch * L * L;
  const float* mq0 = Mq + (size_t)batch * L;
  const float* il0 = invLq + (size_t)batch * L;
  f32x4 acc[2][2] = {};
  int kend = ks * 1024 + 1024;
  for (int k0 = ks * 1024; k0 < kend; k0 += 32) {
    __syncthreads();
#pragma unroll
    for (int i = 0; i < 4; ++i) {
      int R = wid * 64 + i * 16 + (lane >> 2);
      int tap = R >> 7, c = R & 127;
      int chl = (lane & 3) ^ ((R >> 1) & 3);
      const f16* g = bm + (((size_t)(tap * 2 + batch) * CC + c) * L) + k0 + chl * 8;
      gl_lds16(g, Asm + R * 32 + (lane & 3) * 8);
    }
    // B staging: Bt[pp][kk] = attn(k0+kk, p0+pp) with exp fused, 544 tasks
    for (int tau = tid; tau < 544; tau += 512) {
      int kk = tau / 17, ch = tau - kk * 17;
      int k = k0 + kk;
      int pbase = p0 + ch * 8;
      f16 v[8];
      if (mmv[k] != 0.f) {
        const float* trow = Tb + (size_t)k * L + pbase;
        if (pbase + 7 < L) {
          f32x4 t0 = *(const f32x4*)trow;
          f32x4 t1 = *(const f32x4*)(trow + 4);
          f32x4 m0 = *(const f32x4*)(mq0 + pbase);
          f32x4 m1 = *(const f32x4*)(mq0 + pbase + 4);
          f32x4 i0 = *(const f32x4*)(il0 + pbase);
          f32x4 i1 = *(const f32x4*)(il0 + pbase + 4);
#pragma unroll
          for (int e = 0; e < 4; ++e) v[e] = (f16)(__expf(t0[e] - m0[e]) * i0[e]);
#pragma unroll
          for (int e = 0; e < 4; ++e) v[4 + e] = (f16)(__expf(t1[e] - m1[e]) * i1[e]);
        } else {
#pragma unroll
          for (int e = 0; e < 8; ++e) {
            int q = pbase + e;
            v[e] = (q < L) ? (f16)(__expf(trow[e] - mq0[q]) * il0[q]) : (f16)0.f;
          }
        }
      } else {
#pragma unroll
        for (int e = 0; e < 8; ++e) v[e] = (f16)0.f;
      }
#pragma unroll
      for (int e = 0; e < 8; ++e) {
        int pp = ch * 8 + e;
        Bt[pp * 40 + (((kk >> 3) ^ ((pp >> 3) & 3)) * 8) + (kk & 7)] = v[e];
      }
    }
    __syncthreads();
#pragma unroll
    for (int tap = 0; tap < 4; ++tap) {
      int dlt = (tap >> 1) * 64 + (tap & 1);
      f16x8 af[2], bf[2];
#pragma unroll
      for (int m = 0; m < 2; ++m) {
        int R = tap * 128 + wr * 32 + m * 16 + (lane & 15);
        int ph = (lane >> 4) ^ ((R >> 1) & 3);
        af[m] = *(const f16x8*)(Asm + R * 32 + ph * 8);
      }
#pragma unroll
      for (int n = 0; n < 2; ++n) {
        int pp = wc * 32 + n * 16 + (lane & 15) + dlt;
        int ph = (lane >> 4) ^ ((pp >> 3) & 3);
        bf[n] = *(const f16x8*)(Bt + pp * 40 + ph * 8);
      }
#pragma unroll
      for (int m = 0; m < 2; ++m)
#pragma unroll
        for (int n = 0; n < 2; ++n)
          acc[m][n] = __builtin_amdgcn_mfma_f32_16x16x32_f16(af[m], bf[n], acc[m][n], 0, 0, 0);
    }
  }
  int cb = wr * 32 + (lane >> 4) * 4;
  int pb = p0 + wc * 32 + (lane & 15);
#pragma unroll
  for (int m = 0; m < 2; ++m)
#pragma unroll
    for (int n = 0; n < 2; ++n)
#pragma unroll
      for (int r = 0; r < 4; ++r) {
        int c = cb + m * 16 + r;
        int p = pb + n * 16;
        part[(((size_t)ks * 2 + batch) * CC + c) * L + p] = acc[m][n][r];
      }
}

// ---------------- kernel 5b: sum K-split partials, scale, border mask (vectorized) -------
__global__ __launch_bounds__(256) void k_agg_reduce(const float* __restrict__ part, float* __restrict__ out) {
  int idx = (blockIdx.x * 256 + threadIdx.x) * 4;   // 2*128*4096 total
  f32x4 s = {0.f, 0.f, 0.f, 0.f};
#pragma unroll
  for (int ks = 0; ks < 4; ++ks) {
    f32x4 v = *(const f32x4*)(part + (size_t)ks * (2 * CC * L) + idx);
#pragma unroll
    for (int e = 0; e < 4; ++e) s[e] += v[e];
  }
  int p = idx & (L - 1);
  int u = p >> 6, vv = p & 63;
  f32x4 o;
#pragma unroll
  for (int e = 0; e < 4; ++e) o[e] = (u < 63 && (vv + e) < 63) ? s[e] * 0.25f : 0.f;
  *(f32x4*)(out + idx) = o;
}

extern "C" void kernel_launch(void* const* d_in, const int* in_sizes, int n_in,
                              void* d_out, int out_size, void* d_ws, size_t ws_size,
                              hipStream_t stream) {
  const float* f = (const float*)d_in[0];
  const float* b = (const float*)d_in[1];
  const float* mask = (const float*)d_in[2];
  float* out = (float*)d_out;
  char* ws = (char*)d_ws;

  float* T3  = (float*)(ws + 0);           // 134,217,728
  f16* S     = (f16*)(ws + 134217728);     // 67,108,864
  f16* bm    = (f16*)(ws + 201326592);     // 8,388,608
  float* part= (float*)(ws + 209715200);   // 16,777,216
  float* pm  = (float*)(ws + 226492416);   // 8,388,608
  float* pl  = (float*)(ws + 234881024);   // 8,388,608
  float* mmv = (float*)(ws + 243269632);   // 16,384
  float* Mq  = (float*)(ws + 243286016);   // 32,768
  float* iLq = (float*)(ws + 243318784);   // 32,768
  f16* bT    = (f16*)(ws + 243351552);     // 2,097,152
  f16* fT    = (f16*)(ws + 245448704);     // 2,097,152
  float* ssq = (float*)(ws + 247545856);   // 32,768
  float* invn= (float*)(ws + 247578624);   // 32,768
  f16* zp    = (f16*)(ws + 247611392);     // 64

  k_repack<<<dim3(64, 4), dim3(256), 0, stream>>>(b, f, bT, fT, zp);
  k_ssq<<<dim3(16, 2), dim3(256), 0, stream>>>(b, ssq);
  k_norm<<<dim3(32), dim3(256), 0, stream>>>(ssq, invn);
  k_prep_bm<<<dim3(2048), dim3(256), 0, stream>>>(b, bm);
  k_prep_mm<<<dim3(16), dim3(256), 0, stream>>>(mask, mmv);
  k_gemm_scores<<<dim3(32, 32, 2), dim3(256), 0, stream>>>(bT, fT, invn, zp, S);
  k_fuse_stats<<<dim3(2, 256, 2), dim3(256), 0, stream>>>(S, mmv, T3, pm, pl);
  k_fuse_stats_edge<<<dim3(256, 2), dim3(256), 0, stream>>>(S, mmv, T3, pm, pl);
  k_softmax_reduce<<<dim3(128), dim3(256), 0, stream>>>(pm, pl, Mq, iLq);
  k_agg<<<dim3(64, 4, 2), dim3(512), 0, stream>>>(T3, mmv, Mq, iLq, bm, part);
  k_agg_reduce<<<dim3(1024), dim3(256), 0, stream>>>(part, out);
}